// Round 2
// baseline (419.299 us; speedup 1.0000x reference)
//
#include <hip/hip_runtime.h>
#include <math.h>

// HydraAttention R6 — conv_gemm: 2-phase double-buffered LDS (T3-minimum) +
// XCD-aware block swizzle + vectorized mode0 epilogue.
//
// R5 post-mortem: conv_gemm (128^2 implicit GEMM, single-buffer 2-barrier)
// stayed at 90us / MfmaUtil 17% — grid is 512 blocks = 2 blocks/CU, and the
// per-K-step full vmcnt(0) drain exposes load latency (m102 occupancy curve:
// 1/CU=320TF, 2/CU=~430TF, 3/CU=833TF). R6 attacks latency exposure directly:
//   - double-buffered LDS: STAGE(ks+1) issued BEFORE ds_read+MFMA of ks,
//     ONE __syncthreads per step (drain is short because loads had the whole
//     compute phase to land).  [T3-minimum recipe]
//   - XCD swizzle: 512 blocks -> each XCD owns one batch image (2MB, fits
//     4MB L2) -> staging loads become L2 hits -> short drain.  [T1]
//   - conv1 epilogue: corr transposed to [n][m] so the C-write is us4v and
//     the corr read is float4.

typedef unsigned short u16;
typedef __attribute__((ext_vector_type(8))) short short8;
typedef __attribute__((ext_vector_type(4))) float f32x4;
typedef __attribute__((ext_vector_type(4))) unsigned short us4v;

#define ASYNC16(g, l) __builtin_amdgcn_global_load_lds( \
    (const __attribute__((address_space(1))) unsigned int*)(g), \
    (__attribute__((address_space(3))) unsigned int*)(l), 16, 0, 0)

static __device__ __forceinline__ float b2f(u16 h) {
  unsigned int u = ((unsigned int)h) << 16;
  return __builtin_bit_cast(float, u);
}
static __device__ __forceinline__ u16 f2b(float f) {
  unsigned int u = __builtin_bit_cast(unsigned int, f);
  u += 0x7fffu + ((u >> 16) & 1u);
  return (u16)(u >> 16);
}

#define NB 1048576L

// ---------------- prep1: weight converts/reorders + kvbias ----------------
__global__ __launch_bounds__(256) void prep1(
    const float* __restrict__ qw, const float* __restrict__ kw,
    const float* __restrict__ vw, const float* __restrict__ rw,
    const float* __restrict__ c1w, const float* __restrict__ c2w,
    const float* __restrict__ kb, const float* __restrict__ vb,
    u16* __restrict__ qw16, u16* __restrict__ kvw16, u16* __restrict__ rwT16,
    u16* __restrict__ wr1, u16* __restrict__ wr2,
    float* __restrict__ kvbias)
{
  if (blockIdx.x == 5632) {
    int t = threadIdx.x;
    if (t < 512) kvbias[t] = (t < 256) ? kb[t] : vb[t - 256];
    return;
  }
  long g = (long)blockIdx.x * 256 + threadIdx.x;
  if (g < 65536) {
    qw16[g] = f2b(qw[g]);
  } else if (g < 196608) {
    long e = g - 65536;
    kvw16[e] = f2b(e < 65536 ? kw[e] : vw[e - 65536]);
  } else if (g < 262144) {
    long e = g - 196608;
    int cv = e >> 8, co = e & 255;
    rwT16[e] = f2b(rw[co * 256 + cv]);
  } else if (g < 851968) {
    long e = g - 262144;
    int m = e / 2304, r = e - m * 2304;
    int d = r >> 8, c = r & 255;
    wr1[e] = f2b(c1w[m * 2304 + c * 9 + d]);
  } else {
    long e = g - 851968;
    int m = e / 2304, r = e - m * 2304;
    int d = r >> 8, c = r & 255;
    wr2[e] = f2b(c2w[m * 2304 + c * 9 + d]);
  }
}

// T[m*9+t] = sum_co c1w[m][co][t]*rb[co]
__global__ __launch_bounds__(256) void prep_T(
    const float* __restrict__ c1w, const float* __restrict__ rb, float* __restrict__ T)
{
  int e = blockIdx.x * 256 + threadIdx.x;   // 2304
  int m = e / 9, d = e - m * 9;
  float s = 0.f;
  for (int co = 0; co < 256; co++) s += c1w[m * 2304 + co * 9 + d] * rb[co];
  T[e] = s;
}

// corr[p][m] = c1b[m] + sum_{t valid at p} T[m][t]   (TRANSPOSED layout [n][m])
__global__ __launch_bounds__(256) void corr_k(
    const float* __restrict__ T, const float* __restrict__ c1b, float* __restrict__ corr)
{
  int e = blockIdx.x * 256 + threadIdx.x;   // 1048576
  int m = e & 255, p = e >> 8;              // p wave-uniform per block
  int y = p >> 6, xx = p & 63;
  float s = c1b[m];
#pragma unroll
  for (int d = 0; d < 9; d++) {
    int dy = d / 3 - 1, dx = d - (d / 3) * 3 - 1;
    if ((unsigned)(y + dy) < 64u && (unsigned)(xx + dx) < 64u) s += T[m * 9 + d];
  }
  corr[e] = s;                              // corr[p*256 + m], coalesced
}

// ---------------- x [b][c][n] f32 -> xT16 [b][n][c] bf16 ----------------
__global__ __launch_bounds__(256) void transposeX(
    const float* __restrict__ x, u16* __restrict__ xT)
{
  __shared__ float T[64][65];
  int n0 = blockIdx.x * 64, c0 = blockIdx.y * 64, b = blockIdx.z;
  int t = threadIdx.x;
#pragma unroll
  for (int i = 0; i < 4; i++) {
    int c = (t >> 4) + i * 16, nn = (t & 15) * 4;
    float4 v = *(const float4*)&x[(long)b * NB + (long)(c0 + c) * 4096 + n0 + nn];
    T[c][nn] = v.x; T[c][nn + 1] = v.y; T[c][nn + 2] = v.z; T[c][nn + 3] = v.w;
  }
  __syncthreads();
#pragma unroll
  for (int i = 0; i < 4; i++) {
    int n = (t >> 4) + i * 16, cc = (t & 15) * 4;
    us4v o;
#pragma unroll
    for (int e = 0; e < 4; e++) o[e] = f2b(T[cc + e][n]);
    *(us4v*)&xT[(long)b * NB + (long)(n0 + n) * 256 + c0 + cc] = o;
  }
}

// ---------------- generic NT bf16 MFMA GEMM (global_load_lds staging) ----------------
// D[i][j] = sum_k A[i][k]*B[j][k]
// mode 0: v += (p1?p1[row]:0) + (p2?p2[col]:0)
// mode 2: v = (v + p1[b*256+col]) * p2[b*4096+row]
__global__ __launch_bounds__(256) void gemm_nt(
    const u16* __restrict__ A, const u16* __restrict__ B, u16* __restrict__ out,
    int K, int lda, int ldb, long sAb, long sBb, long sOb, long sR, long sC,
    int mode, const float* __restrict__ p1, const float* __restrict__ p2)
{
  __shared__ __align__(16) u16 As[128 * 32];
  __shared__ __align__(16) u16 Bs[128 * 32];
  int b = blockIdx.z;
  long i0 = (long)blockIdx.y * 128;
  long j0 = (long)blockIdx.x * 128;
  const u16* Ab = A + b * sAb + i0 * lda;
  const u16* Bb = B + b * sBb + j0 * ldb;
  int t = threadIdx.x, wave = t >> 6, lane = t & 63;
  int wi = (wave >> 1) * 64, wj = (wave & 1) * 64;
  int li = lane & 15, quad = lane >> 4;
  f32x4 acc[4][4];
#pragma unroll
  for (int i = 0; i < 4; i++)
#pragma unroll
    for (int j = 0; j < 4; j++) acc[i][j] = (f32x4){0.f, 0.f, 0.f, 0.f};

  for (int k0 = 0; k0 < K; k0 += 32) {
#pragma unroll
    for (int h = 0; h < 2; h++) {
      int chunk = wave * 128 + h * 64 + lane;
      int r = chunk >> 2, q = chunk & 3;
      ASYNC16(Ab + (long)r * lda + k0 + q * 8, &As[(wave * 128 + h * 64) * 8]);
      ASYNC16(Bb + (long)r * ldb + k0 + q * 8, &Bs[(wave * 128 + h * 64) * 8]);
    }
    __syncthreads();
    short8 af[4], bf[4];
#pragma unroll
    for (int s = 0; s < 4; s++) af[s] = *(const short8*)&As[(wi + s * 16 + li) * 32 + quad * 8];
#pragma unroll
    for (int s = 0; s < 4; s++) bf[s] = *(const short8*)&Bs[(wj + s * 16 + li) * 32 + quad * 8];
#pragma unroll
    for (int si = 0; si < 4; si++)
#pragma unroll
      for (int sj = 0; sj < 4; sj++)
        acc[si][sj] = __builtin_amdgcn_mfma_f32_16x16x32_bf16(af[si], bf[sj], acc[si][sj], 0, 0, 0);
    __syncthreads();
  }

#pragma unroll
  for (int si = 0; si < 4; si++)
#pragma unroll
    for (int sj = 0; sj < 4; sj++) {
      long col = j0 + wj + sj * 16 + li;
#pragma unroll
      for (int r = 0; r < 4; r++) {
        long row = i0 + wi + si * 16 + quad * 4 + r;
        float v = acc[si][sj][r];
        if (mode == 0) {
          if (p1) v += p1[row];
          if (p2) v += p2[col];
        } else {
          v = (v + p1[b * 256 + col]) * p2[b * 4096 + row];
        }
        out[b * sOb + row * sR + col * sC] = f2b(v);
      }
    }
}

// ---------------- kv split-n GEMM: part[sp][b][cv][ck] f32 ----------------
__global__ __launch_bounds__(256) void gemm_kv(
    const u16* __restrict__ KV, float* __restrict__ part)
{
  __shared__ __align__(16) u16 As[128 * 32];
  __shared__ __align__(16) u16 Bs[128 * 32];
  int z = blockIdx.z;
  int b = z & 7, sp = z >> 3;
  long i0 = (long)blockIdx.y * 128;   // ck
  long j0 = (long)blockIdx.x * 128;   // cv
  const u16* Ab = KV + (long)b * 2 * NB + i0 * 4096;        // K rows
  const u16* Bb = KV + (long)b * 2 * NB + NB + j0 * 4096;   // V rows
  int t = threadIdx.x, wave = t >> 6, lane = t & 63;
  int wi = (wave >> 1) * 64, wj = (wave & 1) * 64;
  int li = lane & 15, quad = lane >> 4;
  f32x4 acc[4][4];
#pragma unroll
  for (int i = 0; i < 4; i++)
#pragma unroll
    for (int j = 0; j < 4; j++) acc[i][j] = (f32x4){0.f, 0.f, 0.f, 0.f};

  int kend = sp * 512 + 512;
  for (int k0 = sp * 512; k0 < kend; k0 += 32) {
#pragma unroll
    for (int h = 0; h < 2; h++) {
      int chunk = wave * 128 + h * 64 + lane;
      int r = chunk >> 2, q = chunk & 3;
      ASYNC16(Ab + (long)r * 4096 + k0 + q * 8, &As[(wave * 128 + h * 64) * 8]);
      ASYNC16(Bb + (long)r * 4096 + k0 + q * 8, &Bs[(wave * 128 + h * 64) * 8]);
    }
    __syncthreads();
    short8 af[4], bf[4];
#pragma unroll
    for (int s = 0; s < 4; s++) af[s] = *(const short8*)&As[(wi + s * 16 + li) * 32 + quad * 8];
#pragma unroll
    for (int s = 0; s < 4; s++) bf[s] = *(const short8*)&Bs[(wj + s * 16 + li) * 32 + quad * 8];
#pragma unroll
    for (int si = 0; si < 4; si++)
#pragma unroll
      for (int sj = 0; sj < 4; sj++)
        acc[si][sj] = __builtin_amdgcn_mfma_f32_16x16x32_bf16(af[si], bf[sj], acc[si][sj], 0, 0, 0);
    __syncthreads();
  }

  float* outp = part + ((long)sp * 8 + b) * 65536;
#pragma unroll
  for (int si = 0; si < 4; si++)
#pragma unroll
    for (int sj = 0; sj < 4; sj++) {
      long col = j0 + wj + sj * 16 + li;   // cv
#pragma unroll
      for (int r = 0; r < 4; r++) {
        long row = i0 + wi + si * 16 + quad * 4 + r;  // ck
        outp[col * 256 + row] = acc[si][sj][r];
      }
    }
}

__global__ __launch_bounds__(256) void reduce_kv(
    const float* __restrict__ part, u16* __restrict__ kvT)
{
  int g = blockIdx.x * 256 + threadIdx.x;  // 524288
  float s = 0.f;
#pragma unroll
  for (int sp = 0; sp < 8; sp++) s += part[(long)sp * 524288 + g];
  kvT[g] = f2b(s);
}

// ---------------- normalize Qt rows ----------------
__global__ __launch_bounds__(256) void normQ(u16* __restrict__ Qt)
{
  int row = blockIdx.x * 4 + (threadIdx.x >> 6);
  int lane = threadIdx.x & 63;
  u16* p = Qt + (long)row * 256 + lane * 4;
  us4v v = *(const us4v*)p;
  float f0 = b2f(v[0]), f1 = b2f(v[1]), f2 = b2f(v[2]), f3 = b2f(v[3]);
  float s = f0 * f0 + f1 * f1 + f2 * f2 + f3 * f3;
#pragma unroll
  for (int m = 32; m; m >>= 1) s += __shfl_xor(s, m, 64);
  float r = 1.0f / sqrtf(s);
  us4v o;
  o[0] = f2b(f0 * r); o[1] = f2b(f1 * r); o[2] = f2b(f2 * r); o[3] = f2b(f3 * r);
  *(us4v*)p = o;
}

// ---------------- K column sumsq -> rsqK[b][n] ----------------
__global__ __launch_bounds__(256) void sumsqK(
    const u16* __restrict__ KV, float* __restrict__ rsqK)
{
  __shared__ float red[8][132];
  int b = blockIdx.x >> 5, nc = blockIdx.x & 31;
  int n0 = nc * 128;
  int t = threadIdx.x;
  int nn = (t & 31) * 4, cg = t >> 5;
  const u16* base = KV + (long)b * 2 * NB;
  float s0 = 0.f, s1 = 0.f, s2 = 0.f, s3 = 0.f;
  for (int st = 0; st < 32; st++) {
    int c = cg + st * 8;
    us4v v = *(const us4v*)(base + (long)c * 4096 + n0 + nn);
    float a = b2f(v[0]), bb = b2f(v[1]), cc = b2f(v[2]), dd = b2f(v[3]);
    s0 = fmaf(a, a, s0); s1 = fmaf(bb, bb, s1);
    s2 = fmaf(cc, cc, s2); s3 = fmaf(dd, dd, s3);
  }
  red[cg][nn] = s0; red[cg][nn + 1] = s1; red[cg][nn + 2] = s2; red[cg][nn + 3] = s3;
  __syncthreads();
  if (t < 128) {
    float s = 0.f;
#pragma unroll
    for (int g = 0; g < 8; g++) s += red[g][t];
    rsqK[b * 4096 + n0 + t] = 1.0f / sqrtf(s);
  }
}

// ---------------- scale K rows by rsqK + ksum; V rows -> vsum ----------------
__global__ __launch_bounds__(256) void scale_sums(
    u16* __restrict__ KV, const float* __restrict__ rsqK,
    float* __restrict__ ksum, float* __restrict__ vsum)
{
  int z = blockIdx.x;
  int isV = z >> 11, rem = z & 2047, b = rem >> 8, c = rem & 255;
  u16* row = KV + (long)b * 2 * NB + (long)isV * NB + (long)c * 4096;
  const float* rq = rsqK + b * 4096;
  int t = threadIdx.x;
  float s = 0.f;
  short8 v0 = *(const short8*)&row[t * 16];
  short8 v1 = *(const short8*)&row[t * 16 + 8];
  if (!isV) {
    short8 o0, o1;
#pragma unroll
    for (int e = 0; e < 8; e++) {
      float a = b2f((u16)v0[e]) * rq[t * 16 + e];
      float bb = b2f((u16)v1[e]) * rq[t * 16 + 8 + e];
      s += a + bb;
      o0[e] = (short)f2b(a); o1[e] = (short)f2b(bb);
    }
    *(short8*)&row[t * 16] = o0;
    *(short8*)&row[t * 16 + 8] = o1;
  } else {
#pragma unroll
    for (int e = 0; e < 8; e++) s += b2f((u16)v0[e]) + b2f((u16)v1[e]);
  }
#pragma unroll
  for (int off = 32; off; off >>= 1) s += __shfl_down(s, off, 64);
  __shared__ float red[4];
  if ((t & 63) == 0) red[t >> 6] = s;
  __syncthreads();
  if (t == 0)
    (isV ? vsum : ksum)[b * 256 + c] = red[0] + red[1] + red[2] + red[3];
}

// ---------------- den[b][n] = 1/(4096 + Qn[n,:].ksum + eps) ----------------
__global__ __launch_bounds__(256) void denom_k(
    const u16* __restrict__ Qt, const float* __restrict__ ksum,
    float* __restrict__ den)
{
  int row = blockIdx.x * 4 + (threadIdx.x >> 6);
  int lane = threadIdx.x & 63;
  int b = row >> 12;
  us4v v = *(const us4v*)(Qt + (long)row * 256 + lane * 4);
  float4 ks = *(const float4*)&ksum[b * 256 + lane * 4];
  float s = b2f(v[0]) * ks.x + b2f(v[1]) * ks.y + b2f(v[2]) * ks.z + b2f(v[3]) * ks.w;
#pragma unroll
  for (int m = 32; m; m >>= 1) s += __shfl_xor(s, m, 64);
  if (lane == 0) den[row] = 1.0f / (4096.0f + s + 1e-6f);
}

// ---------------- conv3x3 as implicit GEMM, 2-phase double-buffered ----------------
// out[m][n] = sum_{d,c} W[m][d*256+c] * img[n + delta(d)][c], K = 2304 (72 steps).
// Double-buffered LDS: stage ks+1 into buf^1 BEFORE compute of ks; single
// __syncthreads per step (its vmcnt/lgkm drain covers both the stage and the
// other waves' ds_reads).  XCD swizzle: each XCD gets one batch image (2MB->L2).
// mode 0: out16[b][n][256] = acc + corrT[n][m]   (us4v store, float4 corr read)
// mode 1: out32[b][m][4096] = (acc + cb[m])*x + x
__global__ __launch_bounds__(256) void conv_gemm(
    const u16* __restrict__ inT, const u16* __restrict__ wr,
    const float* __restrict__ cb, const float* __restrict__ xres,
    u16* __restrict__ out16, float* __restrict__ out32, int mode)
{
  __shared__ __align__(16) u16 As[2][128 * 32];
  __shared__ __align__(16) u16 Bs[2][128 * 32];

  // XCD-aware swizzle: grid (32,2,8) = 512 blocks, 8 XCDs, 64 blocks/XCD.
  // lin%8 == XCD id (round-robin dispatch) -> give each XCD one contiguous
  // chunk = one full batch (32 n-tiles x 2 m-tiles): image 2MB fits L2.
  int lin = blockIdx.x + 32 * blockIdx.y + 64 * blockIdx.z;
  lin = (lin & 7) * 64 + (lin >> 3);
  int b  = lin >> 6;
  int i0 = ((lin >> 5) & 1) * 128;    // m tile
  int n0 = (lin & 31) * 128;          // n tile (2 image rows)

  int t = threadIdx.x, wave = t >> 6, lane = t & 63;
  int wi = (wave >> 1) * 64, wj = (wave & 1) * 64;
  int li = lane & 15, quad = lane >> 4;
  const u16* inb = inT + (long)b * NB;

  // per-thread staging granules (h = 0,1)
  int ch0 = wave * 128 + lane, ch1 = ch0 + 64;
  int r0 = ch0 >> 2, q0 = ch0 & 3;
  int r1 = ch1 >> 2, q1 = ch1 & 3;
  int y0 = (n0 + r0) >> 6, x0 = (n0 + r0) & 63;
  int y1 = (n0 + r1) >> 6, x1 = (n0 + r1) & 63;
  const u16* Ab0 = wr + (long)(i0 + r0) * 2304 + q0 * 8;
  const u16* Ab1 = wr + (long)(i0 + r1) * 2304 + q1 * 8;
  const u16* Bb0 = inb + (long)((y0 << 6) + x0) * 256 + q0 * 8;
  const u16* Bb1 = inb + (long)((y1 << 6) + x1) * 256 + q1 * 8;
  int aoff0 = (wave * 128) * 8;        // u16 offset within one buffer
  int aoff1 = (wave * 128 + 64) * 8;

  f32x4 acc[4][4];
#pragma unroll
  for (int i = 0; i < 4; i++)
#pragma unroll
    for (int j = 0; j < 4; j++) acc[i][j] = (f32x4){0.f, 0.f, 0.f, 0.f};

  const float4 z4 = {0.f, 0.f, 0.f, 0.f};

  // stage K-step ks into buffer buf.  k = ks*32 linear; tap d = ks>>3.
  auto STAGE = [&](int ks, int buf) {
    int d = ks >> 3;
    int dy = d / 3 - 1, dx = d - (d / 3) * 3 - 1;
    long shift = (long)(dy * 64 + dx) * 256;
    int kq = (ks & 7) * 32;
    u16* asb = &As[buf][0];
    u16* bsb = &Bs[buf][0];
    ASYNC16(Ab0 + (long)ks * 32, asb + aoff0);
    ASYNC16(Ab1 + (long)ks * 32, asb + aoff1);
    bool v0 = (unsigned)(y0 + dy) < 64u && (unsigned)(x0 + dx) < 64u;
    bool v1 = (unsigned)(y1 + dy) < 64u && (unsigned)(x1 + dx) < 64u;
    if (v0) ASYNC16(Bb0 + shift + kq, bsb + aoff0);
    else    *(float4*)&bsb[ch0 * 8] = z4;
    if (v1) ASYNC16(Bb1 + shift + kq, bsb + aoff1);
    else    *(float4*)&bsb[ch1 * 8] = z4;
  };

  STAGE(0, 0);
  __syncthreads();                      // drains vmcnt(0)+lgkmcnt(0)

  int cur = 0;
#pragma unroll 1
  for (int ks = 0; ks < 72; ks++) {
    if (ks + 1 < 72) STAGE(ks + 1, cur ^ 1);   // prefetch into other buffer
    const u16* as = &As[cur][0];
    const u16* bs = &Bs[cur][0];
    short8 af[4], bf[4];
#pragma unroll
    for (int s = 0; s < 4; s++) af[s] = *(const short8*)&as[(wi + s * 16 + li) * 32 + quad * 8];
#pragma unroll
    for (int s = 0; s < 4; s++) bf[s] = *(const short8*)&bs[(wj + s * 16 + li) * 32 + quad * 8];
#pragma unroll
    for (int si = 0; si < 4; si++)
#pragma unroll
      for (int sj = 0; sj < 4; sj++)
        acc[si][sj] = __builtin_amdgcn_mfma_f32_16x16x32_bf16(af[si], bf[sj], acc[si][sj], 0, 0, 0);
    __syncthreads();                    // next-step loads landed; reads done
    cur ^= 1;
  }

#pragma unroll
  for (int si = 0; si < 4; si++)
#pragma unroll
    for (int sj = 0; sj < 4; sj++) {
      int col = n0 + wj + sj * 16 + li;              // n
      int row0 = i0 + wi + si * 16 + quad * 4;       // m base (multiple of 4)
      if (mode == 0) {
        f32x4 c4 = *(const f32x4*)&cb[(long)col * 256 + row0];
        us4v o;
#pragma unroll
        for (int r = 0; r < 4; r++) o[r] = f2b(acc[si][sj][r] + c4[r]);
        *(us4v*)&out16[(long)b * NB + (long)col * 256 + row0] = o;
      } else {
#pragma unroll
        for (int r = 0; r < 4; r++) {
          int row = row0 + r;
          float v = acc[si][sj][r] + cb[row];
          long a = (long)b * NB + (long)row * 4096 + col;
          float xv = xres[a];
          out32[a] = fmaf(v, xv, xv);
        }
      }
    }
}

// ---------------- host ----------------
extern "C" void kernel_launch(void* const* d_in, const int* in_sizes, int n_in,
                              void* d_out, int out_size, void* d_ws, size_t ws_size,
                              hipStream_t stream)
{
  const float* x   = (const float*)d_in[0];
  const float* qw  = (const float*)d_in[1];
  const float* qb  = (const float*)d_in[2];
  const float* kw  = (const float*)d_in[3];
  const float* kb  = (const float*)d_in[4];
  const float* vw  = (const float*)d_in[5];
  const float* vb  = (const float*)d_in[6];
  const float* rw  = (const float*)d_in[7];
  const float* rb  = (const float*)d_in[8];
  const float* c1w = (const float*)d_in[9];
  const float* c1b = (const float*)d_in[10];
  const float* c2w = (const float*)d_in[11];
  const float* c2b = (const float*)d_in[12];

  // ws layout (u16 units)
  u16* U     = (u16*)d_ws;
  u16* xT16  = U;                     // 8388608 ; later wvT16
  u16* Qt16  = U + 8388608;           // 8388608 ; later h1T16
  u16* KV16  = U + 16777216;          // 16777216 (K rows 0-255, V rows 256-511 per b)
  u16* wr2   = U + 33554432;          // 589824
  u16* kvT16 = U + 34144256;          // 524288
  float* Fws = (float*)(U + 34668544);
  float* ksum = Fws;                  // 2048
  float* vsum = Fws + 2048;           // 2048

  // d_out scratch (all dead before conv2 writes d_out; conv2 reads NOTHING here)
  char* ob = (char*)d_out;
  float* kvpart = (float*)(ob + 0);           // 16777216 B
  float* den    = (float*)(ob + 16777216);    // 131072
  float* rsqK   = (float*)(ob + 16908288);    // 131072
  float* corr   = (float*)(ob + 17039360);    // 4194304  (layout [n][m])
  u16*   w1p16  = (u16*)(ob + 21233664);      // 1179648
  u16*   wr1    = (u16*)(ob + 22413312);      // 1179648
  float* T      = (float*)(ob + 23592960);    // 36864
  u16*   rwT16  = (u16*)(ob + 23629824);      // 131072
  u16*   qw16   = (u16*)(ob + 23760896);      // 131072
  u16*   kvw16  = (u16*)(ob + 23891968);      // 262144
  float* kvbias = (float*)(ob + 24154112);    // 2048
  float* outF   = (float*)d_out;

  u16* wvT16 = xT16;
  u16* h1T16 = Qt16;

  dim3 blk(256);

  prep1<<<5633, blk, 0, stream>>>(qw, kw, vw, rw, c1w, c2w, kb, vb,
                                  qw16, kvw16, rwT16, wr1, wr2, kvbias);
  prep_T<<<9, blk, 0, stream>>>(c1w, rb, T);
  corr_k<<<4096, blk, 0, stream>>>(T, c1b, corr);
  transposeX<<<dim3(64, 4, 8), blk, 0, stream>>>(x, xT16);

  // w1' = wr1 @ rwT : folds rw into conv1 weights, layout [m][d*256+cv]
  gemm_nt<<<dim3(2, 18, 1), blk, 0, stream>>>(wr1, rwT16, w1p16,
      256, 256, 256, 0L, 0L, 0L, 256L, 1L, 0, nullptr, nullptr);
  // Qt[b][n][ck] = xT @ qw^T + qb
  gemm_nt<<<dim3(2, 32, 8), blk, 0, stream>>>(xT16, qw16, Qt16,
      256, 256, 256, NB, 0L, NB, 256L, 1L, 0, nullptr, qb);
  // KV[b][cq][n] = [kw|vw] @ x + [kb|vb]
  gemm_nt<<<dim3(32, 4, 8), blk, 0, stream>>>(kvw16, xT16, KV16,
      256, 256, 256, 0L, NB, 2 * NB, 4096L, 1L, 0, kvbias, nullptr);

  normQ<<<8192, blk, 0, stream>>>(Qt16);
  sumsqK<<<256, blk, 0, stream>>>(KV16, rsqK);
  scale_sums<<<4096, blk, 0, stream>>>(KV16, rsqK, ksum, vsum);
  denom_k<<<8192, blk, 0, stream>>>(Qt16, ksum, den);

  gemm_kv<<<dim3(2, 2, 64), blk, 0, stream>>>(KV16, kvpart);
  reduce_kv<<<2048, blk, 0, stream>>>(kvpart, kvT16);

  // wvT[b][n][cv] = (Qt @ kv + vsum)*den   (coalesced stores)
  gemm_nt<<<dim3(2, 32, 8), blk, 0, stream>>>(Qt16, kvT16, wvT16,
      256, 256, 256, NB, 65536L, NB, 256L, 1L, 2, vsum, den);

  conv_gemm<<<dim3(32, 2, 8), blk, 0, stream>>>(wvT16, w1p16, corr, nullptr,
                                                h1T16, nullptr, 0);
  conv_gemm<<<dim3(32, 2, 8), blk, 0, stream>>>(h1T16, wr2, c2b, x,
                                                nullptr, outF, 1);
}

// Round 3
// 408.634 us; speedup vs baseline: 1.0261x; 1.0261x over previous
//
#include <hip/hip_runtime.h>
#include <math.h>

// HydraAttention R7 — conv_gemm: 64x128 tile (1024 blocks = 4/CU) +
// triple-buffered LDS with counted s_waitcnt vmcnt(6) (T4, never 0 in loop) +
// zero-page OOB loads (deterministic per-wave vmcnt) + XCD batch swizzle.
//
// R6 post-mortem: conv at 78us, MfmaUtil 20%, occupancy 21% — grid 512 = 2
// blocks/CU was the occupancy cap, and __syncthreads' vmcnt(0) drain gave the
// prefetch only one compute phase to land. R7: 4 blocks/CU by grid/LDS/VGPR,
// and a depth-3 pipeline where stage ks+3 has two compute phases to land;
// raw s_barrier + counted vmcnt keeps loads in flight across barriers.
// Also fixes prep1 kvbias (vb half was never staged; benign since vb==0).

typedef unsigned short u16;
typedef __attribute__((ext_vector_type(8))) short short8;
typedef __attribute__((ext_vector_type(4))) float f32x4;
typedef __attribute__((ext_vector_type(4))) unsigned short us4v;

#define ASYNC16(g, l) __builtin_amdgcn_global_load_lds( \
    (const __attribute__((address_space(1))) unsigned int*)(g), \
    (__attribute__((address_space(3))) unsigned int*)(l), 16, 0, 0)

static __device__ __forceinline__ float b2f(u16 h) {
  unsigned int u = ((unsigned int)h) << 16;
  return __builtin_bit_cast(float, u);
}
static __device__ __forceinline__ u16 f2b(float f) {
  unsigned int u = __builtin_bit_cast(unsigned int, f);
  u += 0x7fffu + ((u >> 16) & 1u);
  return (u16)(u >> 16);
}

#define NB 1048576L

// ---------------- prep1: weight converts/reorders + kvbias + zero page ----------------
__global__ __launch_bounds__(256) void prep1(
    const float* __restrict__ qw, const float* __restrict__ kw,
    const float* __restrict__ vw, const float* __restrict__ rw,
    const float* __restrict__ c1w, const float* __restrict__ c2w,
    const float* __restrict__ kb, const float* __restrict__ vb,
    u16* __restrict__ qw16, u16* __restrict__ kvw16, u16* __restrict__ rwT16,
    u16* __restrict__ wr1, u16* __restrict__ wr2,
    float* __restrict__ kvbias, float* __restrict__ zbuf)
{
  if (blockIdx.x == 5632) {
    int t = threadIdx.x;
    if (t < 256) { kvbias[t] = kb[t]; kvbias[t + 256] = vb[t]; }
    if (t < 64) zbuf[t] = 0.f;
    return;
  }
  long g = (long)blockIdx.x * 256 + threadIdx.x;
  if (g < 65536) {
    qw16[g] = f2b(qw[g]);
  } else if (g < 196608) {
    long e = g - 65536;
    kvw16[e] = f2b(e < 65536 ? kw[e] : vw[e - 65536]);
  } else if (g < 262144) {
    long e = g - 196608;
    int cv = e >> 8, co = e & 255;
    rwT16[e] = f2b(rw[co * 256 + cv]);
  } else if (g < 851968) {
    long e = g - 262144;
    int m = e / 2304, r = e - m * 2304;
    int d = r >> 8, c = r & 255;
    wr1[e] = f2b(c1w[m * 2304 + c * 9 + d]);
  } else {
    long e = g - 851968;
    int m = e / 2304, r = e - m * 2304;
    int d = r >> 8, c = r & 255;
    wr2[e] = f2b(c2w[m * 2304 + c * 9 + d]);
  }
}

// T[m*9+t] = sum_co c1w[m][co][t]*rb[co]
__global__ __launch_bounds__(256) void prep_T(
    const float* __restrict__ c1w, const float* __restrict__ rb, float* __restrict__ T)
{
  int e = blockIdx.x * 256 + threadIdx.x;   // 2304
  int m = e / 9, d = e - m * 9;
  float s = 0.f;
  for (int co = 0; co < 256; co++) s += c1w[m * 2304 + co * 9 + d] * rb[co];
  T[e] = s;
}

// corr[p][m] = c1b[m] + sum_{t valid at p} T[m][t]   (TRANSPOSED layout [n][m])
__global__ __launch_bounds__(256) void corr_k(
    const float* __restrict__ T, const float* __restrict__ c1b, float* __restrict__ corr)
{
  int e = blockIdx.x * 256 + threadIdx.x;   // 1048576
  int m = e & 255, p = e >> 8;
  int y = p >> 6, xx = p & 63;
  float s = c1b[m];
#pragma unroll
  for (int d = 0; d < 9; d++) {
    int dy = d / 3 - 1, dx = d - (d / 3) * 3 - 1;
    if ((unsigned)(y + dy) < 64u && (unsigned)(xx + dx) < 64u) s += T[m * 9 + d];
  }
  corr[e] = s;                              // corr[p*256 + m], coalesced
}

// ---------------- x [b][c][n] f32 -> xT16 [b][n][c] bf16 ----------------
__global__ __launch_bounds__(256) void transposeX(
    const float* __restrict__ x, u16* __restrict__ xT)
{
  __shared__ float T[64][65];
  int n0 = blockIdx.x * 64, c0 = blockIdx.y * 64, b = blockIdx.z;
  int t = threadIdx.x;
#pragma unroll
  for (int i = 0; i < 4; i++) {
    int c = (t >> 4) + i * 16, nn = (t & 15) * 4;
    float4 v = *(const float4*)&x[(long)b * NB + (long)(c0 + c) * 4096 + n0 + nn];
    T[c][nn] = v.x; T[c][nn + 1] = v.y; T[c][nn + 2] = v.z; T[c][nn + 3] = v.w;
  }
  __syncthreads();
#pragma unroll
  for (int i = 0; i < 4; i++) {
    int n = (t >> 4) + i * 16, cc = (t & 15) * 4;
    us4v o;
#pragma unroll
    for (int e = 0; e < 4; e++) o[e] = f2b(T[cc + e][n]);
    *(us4v*)&xT[(long)b * NB + (long)(n0 + n) * 256 + c0 + cc] = o;
  }
}

// ---------------- generic NT bf16 MFMA GEMM (global_load_lds staging) ----------------
// D[i][j] = sum_k A[i][k]*B[j][k]
// mode 0: v += (p1?p1[row]:0) + (p2?p2[col]:0)
// mode 2: v = (v + p1[b*256+col]) * p2[b*4096+row]
__global__ __launch_bounds__(256) void gemm_nt(
    const u16* __restrict__ A, const u16* __restrict__ B, u16* __restrict__ out,
    int K, int lda, int ldb, long sAb, long sBb, long sOb, long sR, long sC,
    int mode, const float* __restrict__ p1, const float* __restrict__ p2)
{
  __shared__ __align__(16) u16 As[128 * 32];
  __shared__ __align__(16) u16 Bs[128 * 32];
  int b = blockIdx.z;
  long i0 = (long)blockIdx.y * 128;
  long j0 = (long)blockIdx.x * 128;
  const u16* Ab = A + b * sAb + i0 * lda;
  const u16* Bb = B + b * sBb + j0 * ldb;
  int t = threadIdx.x, wave = t >> 6, lane = t & 63;
  int wi = (wave >> 1) * 64, wj = (wave & 1) * 64;
  int li = lane & 15, quad = lane >> 4;
  f32x4 acc[4][4];
#pragma unroll
  for (int i = 0; i < 4; i++)
#pragma unroll
    for (int j = 0; j < 4; j++) acc[i][j] = (f32x4){0.f, 0.f, 0.f, 0.f};

  for (int k0 = 0; k0 < K; k0 += 32) {
#pragma unroll
    for (int h = 0; h < 2; h++) {
      int chunk = wave * 128 + h * 64 + lane;
      int r = chunk >> 2, q = chunk & 3;
      ASYNC16(Ab + (long)r * lda + k0 + q * 8, &As[(wave * 128 + h * 64) * 8]);
      ASYNC16(Bb + (long)r * ldb + k0 + q * 8, &Bs[(wave * 128 + h * 64) * 8]);
    }
    __syncthreads();
    short8 af[4], bf[4];
#pragma unroll
    for (int s = 0; s < 4; s++) af[s] = *(const short8*)&As[(wi + s * 16 + li) * 32 + quad * 8];
#pragma unroll
    for (int s = 0; s < 4; s++) bf[s] = *(const short8*)&Bs[(wj + s * 16 + li) * 32 + quad * 8];
#pragma unroll
    for (int si = 0; si < 4; si++)
#pragma unroll
      for (int sj = 0; sj < 4; sj++)
        acc[si][sj] = __builtin_amdgcn_mfma_f32_16x16x32_bf16(af[si], bf[sj], acc[si][sj], 0, 0, 0);
    __syncthreads();
  }

#pragma unroll
  for (int si = 0; si < 4; si++)
#pragma unroll
    for (int sj = 0; sj < 4; sj++) {
      long col = j0 + wj + sj * 16 + li;
#pragma unroll
      for (int r = 0; r < 4; r++) {
        long row = i0 + wi + si * 16 + quad * 4 + r;
        float v = acc[si][sj][r];
        if (mode == 0) {
          if (p1) v += p1[row];
          if (p2) v += p2[col];
        } else {
          v = (v + p1[b * 256 + col]) * p2[b * 4096 + row];
        }
        out[b * sOb + row * sR + col * sC] = f2b(v);
      }
    }
}

// ---------------- kv split-n GEMM: part[sp][b][cv][ck] f32 ----------------
__global__ __launch_bounds__(256) void gemm_kv(
    const u16* __restrict__ KV, float* __restrict__ part)
{
  __shared__ __align__(16) u16 As[128 * 32];
  __shared__ __align__(16) u16 Bs[128 * 32];
  int z = blockIdx.z;
  int b = z & 7, sp = z >> 3;
  long i0 = (long)blockIdx.y * 128;   // ck
  long j0 = (long)blockIdx.x * 128;   // cv
  const u16* Ab = KV + (long)b * 2 * NB + i0 * 4096;        // K rows
  const u16* Bb = KV + (long)b * 2 * NB + NB + j0 * 4096;   // V rows
  int t = threadIdx.x, wave = t >> 6, lane = t & 63;
  int wi = (wave >> 1) * 64, wj = (wave & 1) * 64;
  int li = lane & 15, quad = lane >> 4;
  f32x4 acc[4][4];
#pragma unroll
  for (int i = 0; i < 4; i++)
#pragma unroll
    for (int j = 0; j < 4; j++) acc[i][j] = (f32x4){0.f, 0.f, 0.f, 0.f};

  int kend = sp * 512 + 512;
  for (int k0 = sp * 512; k0 < kend; k0 += 32) {
#pragma unroll
    for (int h = 0; h < 2; h++) {
      int chunk = wave * 128 + h * 64 + lane;
      int r = chunk >> 2, q = chunk & 3;
      ASYNC16(Ab + (long)r * 4096 + k0 + q * 8, &As[(wave * 128 + h * 64) * 8]);
      ASYNC16(Bb + (long)r * 4096 + k0 + q * 8, &Bs[(wave * 128 + h * 64) * 8]);
    }
    __syncthreads();
    short8 af[4], bf[4];
#pragma unroll
    for (int s = 0; s < 4; s++) af[s] = *(const short8*)&As[(wi + s * 16 + li) * 32 + quad * 8];
#pragma unroll
    for (int s = 0; s < 4; s++) bf[s] = *(const short8*)&Bs[(wj + s * 16 + li) * 32 + quad * 8];
#pragma unroll
    for (int si = 0; si < 4; si++)
#pragma unroll
      for (int sj = 0; sj < 4; sj++)
        acc[si][sj] = __builtin_amdgcn_mfma_f32_16x16x32_bf16(af[si], bf[sj], acc[si][sj], 0, 0, 0);
    __syncthreads();
  }

  float* outp = part + ((long)sp * 8 + b) * 65536;
#pragma unroll
  for (int si = 0; si < 4; si++)
#pragma unroll
    for (int sj = 0; sj < 4; sj++) {
      long col = j0 + wj + sj * 16 + li;   // cv
#pragma unroll
      for (int r = 0; r < 4; r++) {
        long row = i0 + wi + si * 16 + quad * 4 + r;  // ck
        outp[col * 256 + row] = acc[si][sj][r];
      }
    }
}

__global__ __launch_bounds__(256) void reduce_kv(
    const float* __restrict__ part, u16* __restrict__ kvT)
{
  int g = blockIdx.x * 256 + threadIdx.x;  // 524288
  float s = 0.f;
#pragma unroll
  for (int sp = 0; sp < 8; sp++) s += part[(long)sp * 524288 + g];
  kvT[g] = f2b(s);
}

// ---------------- normalize Qt rows ----------------
__global__ __launch_bounds__(256) void normQ(u16* __restrict__ Qt)
{
  int row = blockIdx.x * 4 + (threadIdx.x >> 6);
  int lane = threadIdx.x & 63;
  u16* p = Qt + (long)row * 256 + lane * 4;
  us4v v = *(const us4v*)p;
  float f0 = b2f(v[0]), f1 = b2f(v[1]), f2 = b2f(v[2]), f3 = b2f(v[3]);
  float s = f0 * f0 + f1 * f1 + f2 * f2 + f3 * f3;
#pragma unroll
  for (int m = 32; m; m >>= 1) s += __shfl_xor(s, m, 64);
  float r = 1.0f / sqrtf(s);
  us4v o;
  o[0] = f2b(f0 * r); o[1] = f2b(f1 * r); o[2] = f2b(f2 * r); o[3] = f2b(f3 * r);
  *(us4v*)p = o;
}

// ---------------- K column sumsq -> rsqK[b][n] ----------------
__global__ __launch_bounds__(256) void sumsqK(
    const u16* __restrict__ KV, float* __restrict__ rsqK)
{
  __shared__ float red[8][132];
  int b = blockIdx.x >> 5, nc = blockIdx.x & 31;
  int n0 = nc * 128;
  int t = threadIdx.x;
  int nn = (t & 31) * 4, cg = t >> 5;
  const u16* base = KV + (long)b * 2 * NB;
  float s0 = 0.f, s1 = 0.f, s2 = 0.f, s3 = 0.f;
  for (int st = 0; st < 32; st++) {
    int c = cg + st * 8;
    us4v v = *(const us4v*)(base + (long)c * 4096 + n0 + nn);
    float a = b2f(v[0]), bb = b2f(v[1]), cc = b2f(v[2]), dd = b2f(v[3]);
    s0 = fmaf(a, a, s0); s1 = fmaf(bb, bb, s1);
    s2 = fmaf(cc, cc, s2); s3 = fmaf(dd, dd, s3);
  }
  red[cg][nn] = s0; red[cg][nn + 1] = s1; red[cg][nn + 2] = s2; red[cg][nn + 3] = s3;
  __syncthreads();
  if (t < 128) {
    float s = 0.f;
#pragma unroll
    for (int g = 0; g < 8; g++) s += red[g][t];
    rsqK[b * 4096 + n0 + t] = 1.0f / sqrtf(s);
  }
}

// ---------------- scale K rows by rsqK + ksum; V rows -> vsum ----------------
__global__ __launch_bounds__(256) void scale_sums(
    u16* __restrict__ KV, const float* __restrict__ rsqK,
    float* __restrict__ ksum, float* __restrict__ vsum)
{
  int z = blockIdx.x;
  int isV = z >> 11, rem = z & 2047, b = rem >> 8, c = rem & 255;
  u16* row = KV + (long)b * 2 * NB + (long)isV * NB + (long)c * 4096;
  const float* rq = rsqK + b * 4096;
  int t = threadIdx.x;
  float s = 0.f;
  short8 v0 = *(const short8*)&row[t * 16];
  short8 v1 = *(const short8*)&row[t * 16 + 8];
  if (!isV) {
    short8 o0, o1;
#pragma unroll
    for (int e = 0; e < 8; e++) {
      float a = b2f((u16)v0[e]) * rq[t * 16 + e];
      float bb = b2f((u16)v1[e]) * rq[t * 16 + 8 + e];
      s += a + bb;
      o0[e] = (short)f2b(a); o1[e] = (short)f2b(bb);
    }
    *(short8*)&row[t * 16] = o0;
    *(short8*)&row[t * 16 + 8] = o1;
  } else {
#pragma unroll
    for (int e = 0; e < 8; e++) s += b2f((u16)v0[e]) + b2f((u16)v1[e]);
  }
#pragma unroll
  for (int off = 32; off; off >>= 1) s += __shfl_down(s, off, 64);
  __shared__ float red[4];
  if ((t & 63) == 0) red[t >> 6] = s;
  __syncthreads();
  if (t == 0)
    (isV ? vsum : ksum)[b * 256 + c] = red[0] + red[1] + red[2] + red[3];
}

// ---------------- den[b][n] = 1/(4096 + Qn[n,:].ksum + eps) ----------------
__global__ __launch_bounds__(256) void denom_k(
    const u16* __restrict__ Qt, const float* __restrict__ ksum,
    float* __restrict__ den)
{
  int row = blockIdx.x * 4 + (threadIdx.x >> 6);
  int lane = threadIdx.x & 63;
  int b = row >> 12;
  us4v v = *(const us4v*)(Qt + (long)row * 256 + lane * 4);
  float4 ks = *(const float4*)&ksum[b * 256 + lane * 4];
  float s = b2f(v[0]) * ks.x + b2f(v[1]) * ks.y + b2f(v[2]) * ks.z + b2f(v[3]) * ks.w;
#pragma unroll
  for (int m = 32; m; m >>= 1) s += __shfl_xor(s, m, 64);
  if (lane == 0) den[row] = 1.0f / (4096.0f + s + 1e-6f);
}

// ---------------- conv3x3 implicit GEMM: 64x128 tile, depth-3 counted-vmcnt ----------------
// out[m][n] = sum_{d,c} W[m][d*256+c] * img[n + delta(d)][c], K = 2304 (72 steps).
// Triple-buffered LDS (3 x [A 64x32 | B 128x32] = 36KB). Per K-step per thread:
// exactly 3 ASYNC16 (1 A-granule + 2 B-granules); OOB halo granules load from a
// zero page so vmcnt counts are deterministic. Main loop: s_waitcnt vmcnt(6)
// (2 stages in flight) + raw s_barrier; stage ks+3 issued after compute of ks
// -> two compute phases to hide latency. Tail peeled with vmcnt(6)/(3)/(0).
// Grid 1024 (= 4 blocks/CU); lin&7 -> batch == XCD (round-robin dispatch).
// mode 0: out16[b][n][256] = acc + corrT[n][m]   (us4v store, f32x4 corr read)
// mode 1: out32[b][m][4096] = (acc + cb[m])*x + x
__global__ __launch_bounds__(256, 4) void conv_gemm(
    const u16* __restrict__ inT, const u16* __restrict__ wr,
    const float* __restrict__ cb, const float* __restrict__ xres,
    const float* __restrict__ zbuf,
    u16* __restrict__ out16, float* __restrict__ out32, int mode)
{
  __shared__ __align__(16) u16 S[3 * 6144];   // per buf: A[64][32] @0, B[128][32] @2048

  int lin = blockIdx.x;            // 1024 blocks
  int b   = lin & 7;               // == XCD id under round-robin dispatch
  int idx = lin >> 3;              // 0..127 ; m fastest (B-tile reuse across m)
  int i0  = (idx & 3) * 64;        // m tile
  int n0  = (idx >> 2) * 128;      // n tile = 2 image rows

  int t = threadIdx.x, wave = t >> 6, lane = t & 63;
  int wi = (wave >> 1) * 32, wj = (wave & 1) * 64;
  int li = lane & 15, quad = lane >> 4;
  const u16* inb = inT + (long)b * NB;

  // per-thread staging addresses (granule = 16B = 8 ch)
  const u16* Ag  = wr  + (long)(i0 + (t >> 2)) * 2304 + (t & 3) * 8;
  const u16* Bg0 = inb + (long)(n0 + (t >> 2)) * 256 + (t & 3) * 8;
  const u16* Bg1 = Bg0 + 64 * 256;
  const u16* zp  = (const u16*)zbuf + (t & 3) * 8;
  int yb0 = n0 >> 6, yb1 = yb0 + 1, xb = t >> 2;   // xb = x coord (0..63)

  f32x4 acc[2][4];
#pragma unroll
  for (int i = 0; i < 2; i++)
#pragma unroll
    for (int j = 0; j < 4; j++) acc[i][j] = (f32x4){0.f, 0.f, 0.f, 0.f};

  // stage K-step ks into buffer buf: ALWAYS 3 loads per thread.
  auto STAGE = [&](int ks, int buf) {
    int d = ks >> 3;
    int dy = d / 3 - 1, dx = d - (d / 3) * 3 - 1;
    long shift = (long)(dy * 64 + dx) * 256 + (ks & 7) * 32;
    u16* base = &S[buf * 6144];
    ASYNC16(Ag + (long)ks * 32, base + wave * 512);
    const u16* s0 = ((unsigned)(yb0 + dy) < 64u && (unsigned)(xb + dx) < 64u)
                    ? Bg0 + shift : zp;
    const u16* s1 = ((unsigned)(yb1 + dy) < 64u && (unsigned)(xb + dx) < 64u)
                    ? Bg1 + shift : zp;
    ASYNC16(s0, base + 2048 + wave * 512);
    ASYNC16(s1, base + 4096 + wave * 512);
  };

  auto COMPUTE = [&](int buf) {
    const u16* as = &S[buf * 6144];
    const u16* bs = as + 2048;
    short8 af[2], bf[4];
#pragma unroll
    for (int s = 0; s < 2; s++) af[s] = *(const short8*)&as[(wi + s * 16 + li) * 32 + quad * 8];
#pragma unroll
    for (int s = 0; s < 4; s++) bf[s] = *(const short8*)&bs[(wj + s * 16 + li) * 32 + quad * 8];
#pragma unroll
    for (int si = 0; si < 2; si++)
#pragma unroll
      for (int sj = 0; sj < 4; sj++)
        acc[si][sj] = __builtin_amdgcn_mfma_f32_16x16x32_bf16(af[si], bf[sj], acc[si][sj], 0, 0, 0);
  };

  STAGE(0, 0); STAGE(1, 1); STAGE(2, 2);   // 9 loads in flight

  int cur = 0;
#pragma unroll 1
  for (int ks = 0; ks < 69; ks++) {
    asm volatile("s_waitcnt vmcnt(6)" ::: "memory");   // stage ks landed (mine)
    __builtin_amdgcn_s_barrier();                      // everyone's landed
    COMPUTE(cur);
    __builtin_amdgcn_s_barrier();                      // all reads of buf done
    STAGE(ks + 3, cur);                                // overwrite freed buffer
    cur = (cur == 2) ? 0 : cur + 1;
  }
  // ks = 69: stages 70,71 in flight (6)
  asm volatile("s_waitcnt vmcnt(6)" ::: "memory");
  __builtin_amdgcn_s_barrier();
  COMPUTE(cur);
  cur = (cur == 2) ? 0 : cur + 1;
  // ks = 70: stage 71 in flight (3)
  asm volatile("s_waitcnt vmcnt(3)" ::: "memory");
  __builtin_amdgcn_s_barrier();
  COMPUTE(cur);
  cur = (cur == 2) ? 0 : cur + 1;
  // ks = 71
  asm volatile("s_waitcnt vmcnt(0)" ::: "memory");
  __builtin_amdgcn_s_barrier();
  COMPUTE(cur);

#pragma unroll
  for (int si = 0; si < 2; si++)
#pragma unroll
    for (int sj = 0; sj < 4; sj++) {
      int col = n0 + wj + sj * 16 + li;              // n
      int row0 = i0 + wi + si * 16 + quad * 4;       // m base (multiple of 4)
      if (mode == 0) {
        f32x4 c4 = *(const f32x4*)&cb[(long)col * 256 + row0];
        us4v o;
#pragma unroll
        for (int r = 0; r < 4; r++) o[r] = f2b(acc[si][sj][r] + c4[r]);
        *(us4v*)&out16[(long)b * NB + (long)col * 256 + row0] = o;
      } else {
#pragma unroll
        for (int r = 0; r < 4; r++) {
          int row = row0 + r;
          float v = acc[si][sj][r] + cb[row];
          long a = (long)b * NB + (long)row * 4096 + col;
          float xv = xres[a];
          out32[a] = fmaf(v, xv, xv);
        }
      }
    }
}

// ---------------- host ----------------
extern "C" void kernel_launch(void* const* d_in, const int* in_sizes, int n_in,
                              void* d_out, int out_size, void* d_ws, size_t ws_size,
                              hipStream_t stream)
{
  const float* x   = (const float*)d_in[0];
  const float* qw  = (const float*)d_in[1];
  const float* qb  = (const float*)d_in[2];
  const float* kw  = (const float*)d_in[3];
  const float* kb  = (const float*)d_in[4];
  const float* vw  = (const float*)d_in[5];
  const float* vb  = (const float*)d_in[6];
  const float* rw  = (const float*)d_in[7];
  const float* rb  = (const float*)d_in[8];
  const float* c1w = (const float*)d_in[9];
  const float* c1b = (const float*)d_in[10];
  const float* c2w = (const float*)d_in[11];
  const float* c2b = (const float*)d_in[12];

  // ws layout (u16 units)
  u16* U     = (u16*)d_ws;
  u16* xT16  = U;                     // 8388608 ; later wvT16
  u16* Qt16  = U + 8388608;           // 8388608 ; later h1T16
  u16* KV16  = U + 16777216;          // 16777216 (K rows 0-255, V rows 256-511 per b)
  u16* wr2   = U + 33554432;          // 589824
  u16* kvT16 = U + 34144256;          // 524288
  float* Fws = (float*)(U + 34668544);
  float* ksum = Fws;                  // 2048
  float* vsum = Fws + 2048;           // 2048
  float* zbuf = Fws + 4096;           // 64 (zero page for conv OOB loads)

  // d_out scratch (all dead before conv2 writes d_out; conv2 reads NOTHING here)
  char* ob = (char*)d_out;
  float* kvpart = (float*)(ob + 0);           // 16777216 B
  float* den    = (float*)(ob + 16777216);    // 131072
  float* rsqK   = (float*)(ob + 16908288);    // 131072
  float* corr   = (float*)(ob + 17039360);    // 4194304  (layout [n][m])
  u16*   w1p16  = (u16*)(ob + 21233664);      // 1179648
  u16*   wr1    = (u16*)(ob + 22413312);      // 1179648
  float* T      = (float*)(ob + 23592960);    // 36864
  u16*   rwT16  = (u16*)(ob + 23629824);      // 131072
  u16*   qw16   = (u16*)(ob + 23760896);      // 131072
  u16*   kvw16  = (u16*)(ob + 23891968);      // 262144
  float* kvbias = (float*)(ob + 24154112);    // 2048
  float* outF   = (float*)d_out;

  u16* wvT16 = xT16;
  u16* h1T16 = Qt16;

  dim3 blk(256);

  prep1<<<5633, blk, 0, stream>>>(qw, kw, vw, rw, c1w, c2w, kb, vb,
                                  qw16, kvw16, rwT16, wr1, wr2, kvbias, zbuf);
  prep_T<<<9, blk, 0, stream>>>(c1w, rb, T);
  corr_k<<<4096, blk, 0, stream>>>(T, c1b, corr);
  transposeX<<<dim3(64, 4, 8), blk, 0, stream>>>(x, xT16);

  // w1' = wr1 @ rwT : folds rw into conv1 weights, layout [m][d*256+cv]
  gemm_nt<<<dim3(2, 18, 1), blk, 0, stream>>>(wr1, rwT16, w1p16,
      256, 256, 256, 0L, 0L, 0L, 256L, 1L, 0, nullptr, nullptr);
  // Qt[b][n][ck] = xT @ qw^T + qb
  gemm_nt<<<dim3(2, 32, 8), blk, 0, stream>>>(xT16, qw16, Qt16,
      256, 256, 256, NB, 0L, NB, 256L, 1L, 0, nullptr, qb);
  // KV[b][cq][n] = [kw|vw] @ x + [kb|vb]
  gemm_nt<<<dim3(32, 4, 8), blk, 0, stream>>>(kvw16, xT16, KV16,
      256, 256, 256, 0L, NB, 2 * NB, 4096L, 1L, 0, kvbias, nullptr);

  normQ<<<8192, blk, 0, stream>>>(Qt16);
  sumsqK<<<256, blk, 0, stream>>>(KV16, rsqK);
  scale_sums<<<4096, blk, 0, stream>>>(KV16, rsqK, ksum, vsum);
  denom_k<<<8192, blk, 0, stream>>>(Qt16, ksum, den);

  gemm_kv<<<dim3(2, 2, 64), blk, 0, stream>>>(KV16, kvpart);
  reduce_kv<<<2048, blk, 0, stream>>>(kvpart, kvT16);

  // wvT[b][n][cv] = (Qt @ kv + vsum)*den   (coalesced stores)
  gemm_nt<<<dim3(2, 32, 8), blk, 0, stream>>>(Qt16, kvT16, wvT16,
      256, 256, 256, NB, 65536L, NB, 256L, 1L, 2, vsum, den);

  conv_gemm<<<1024, blk, 0, stream>>>(wvT16, w1p16, corr, nullptr, zbuf,
                                      h1T16, nullptr, 0);
  conv_gemm<<<1024, blk, 0, stream>>>(h1T16, wr2, c2b, x, zbuf,
                                      nullptr, outF, 1);
}

// Round 4
// 406.058 us; speedup vs baseline: 1.0326x; 1.0063x over previous
//
#include <hip/hip_runtime.h>
#include <math.h>

// HydraAttention R8 — T2 LDS XOR swizzle (2-way-free variant) on all MFMA
// kernels (conv_gemm, gemm_nt, gemm_kv).
//
// R7 post-mortem: conv at 74.5us, occupancy fixed (33%) but MfmaUtil 21% and
// SQ_LDS_BANK_CONFLICT 7.08M — every fragment ds_read_b128 is 8-way bank
// conflicted (addr = row*64B + quad*16B -> 8 lanes per 4-bank group; m136:
// 2.94x). Per-step arithmetic: LDS 98KB/CU-step = 1156cyc clean, ~2650cyc
// conflicted vs 2486cyc observed -> conflict-bound.
// Fix: store quad_phys = quad ^ ((row>>1)&3) (byte ^= ((byte>>7)&3)<<4).
// Both-sides-or-neither (rule #21): LDS dest stays linear (global_load_lds),
// SOURCE column pre-swizzled. Granule index == thread id everywhere, so:
//   stage: qs = (t&3)^((t>>3)&3)   (thread-local constant)
//   read:  qx = quad ^ ((lane>>1)&3)
// Row/validity logic untouched; zero extra per-read cost. After swizzle the
// 16 rows of a fragment read use each quad-slot exactly 2x -> 2-way = free.

typedef unsigned short u16;
typedef __attribute__((ext_vector_type(8))) short short8;
typedef __attribute__((ext_vector_type(4))) float f32x4;
typedef __attribute__((ext_vector_type(4))) unsigned short us4v;

#define ASYNC16(g, l) __builtin_amdgcn_global_load_lds( \
    (const __attribute__((address_space(1))) unsigned int*)(g), \
    (__attribute__((address_space(3))) unsigned int*)(l), 16, 0, 0)

static __device__ __forceinline__ float b2f(u16 h) {
  unsigned int u = ((unsigned int)h) << 16;
  return __builtin_bit_cast(float, u);
}
static __device__ __forceinline__ u16 f2b(float f) {
  unsigned int u = __builtin_bit_cast(unsigned int, f);
  u += 0x7fffu + ((u >> 16) & 1u);
  return (u16)(u >> 16);
}

#define NB 1048576L

// ---------------- prep1: weight converts/reorders + kvbias + zero page ----------------
__global__ __launch_bounds__(256) void prep1(
    const float* __restrict__ qw, const float* __restrict__ kw,
    const float* __restrict__ vw, const float* __restrict__ rw,
    const float* __restrict__ c1w, const float* __restrict__ c2w,
    const float* __restrict__ kb, const float* __restrict__ vb,
    u16* __restrict__ qw16, u16* __restrict__ kvw16, u16* __restrict__ rwT16,
    u16* __restrict__ wr1, u16* __restrict__ wr2,
    float* __restrict__ kvbias, float* __restrict__ zbuf)
{
  if (blockIdx.x == 5632) {
    int t = threadIdx.x;
    if (t < 256) { kvbias[t] = kb[t]; kvbias[t + 256] = vb[t]; }
    if (t < 64) zbuf[t] = 0.f;
    return;
  }
  long g = (long)blockIdx.x * 256 + threadIdx.x;
  if (g < 65536) {
    qw16[g] = f2b(qw[g]);
  } else if (g < 196608) {
    long e = g - 65536;
    kvw16[e] = f2b(e < 65536 ? kw[e] : vw[e - 65536]);
  } else if (g < 262144) {
    long e = g - 196608;
    int cv = e >> 8, co = e & 255;
    rwT16[e] = f2b(rw[co * 256 + cv]);
  } else if (g < 851968) {
    long e = g - 262144;
    int m = e / 2304, r = e - m * 2304;
    int d = r >> 8, c = r & 255;
    wr1[e] = f2b(c1w[m * 2304 + c * 9 + d]);
  } else {
    long e = g - 851968;
    int m = e / 2304, r = e - m * 2304;
    int d = r >> 8, c = r & 255;
    wr2[e] = f2b(c2w[m * 2304 + c * 9 + d]);
  }
}

// T[m*9+t] = sum_co c1w[m][co][t]*rb[co]
__global__ __launch_bounds__(256) void prep_T(
    const float* __restrict__ c1w, const float* __restrict__ rb, float* __restrict__ T)
{
  int e = blockIdx.x * 256 + threadIdx.x;   // 2304
  int m = e / 9, d = e - m * 9;
  float s = 0.f;
  for (int co = 0; co < 256; co++) s += c1w[m * 2304 + co * 9 + d] * rb[co];
  T[e] = s;
}

// corr[p][m] = c1b[m] + sum_{t valid at p} T[m][t]   (TRANSPOSED layout [n][m])
__global__ __launch_bounds__(256) void corr_k(
    const float* __restrict__ T, const float* __restrict__ c1b, float* __restrict__ corr)
{
  int e = blockIdx.x * 256 + threadIdx.x;   // 1048576
  int m = e & 255, p = e >> 8;
  int y = p >> 6, xx = p & 63;
  float s = c1b[m];
#pragma unroll
  for (int d = 0; d < 9; d++) {
    int dy = d / 3 - 1, dx = d - (d / 3) * 3 - 1;
    if ((unsigned)(y + dy) < 64u && (unsigned)(xx + dx) < 64u) s += T[m * 9 + d];
  }
  corr[e] = s;                              // corr[p*256 + m], coalesced
}

// ---------------- x [b][c][n] f32 -> xT16 [b][n][c] bf16 ----------------
__global__ __launch_bounds__(256) void transposeX(
    const float* __restrict__ x, u16* __restrict__ xT)
{
  __shared__ float T[64][65];
  int n0 = blockIdx.x * 64, c0 = blockIdx.y * 64, b = blockIdx.z;
  int t = threadIdx.x;
#pragma unroll
  for (int i = 0; i < 4; i++) {
    int c = (t >> 4) + i * 16, nn = (t & 15) * 4;
    float4 v = *(const float4*)&x[(long)b * NB + (long)(c0 + c) * 4096 + n0 + nn];
    T[c][nn] = v.x; T[c][nn + 1] = v.y; T[c][nn + 2] = v.z; T[c][nn + 3] = v.w;
  }
  __syncthreads();
#pragma unroll
  for (int i = 0; i < 4; i++) {
    int n = (t >> 4) + i * 16, cc = (t & 15) * 4;
    us4v o;
#pragma unroll
    for (int e = 0; e < 4; e++) o[e] = f2b(T[cc + e][n]);
    *(us4v*)&xT[(long)b * NB + (long)(n0 + n) * 256 + c0 + cc] = o;
  }
}

// ---------------- generic NT bf16 MFMA GEMM (global_load_lds staging, T2 swizzle) ----------------
// D[i][j] = sum_k A[i][k]*B[j][k]
// mode 0: v += (p1?p1[row]:0) + (p2?p2[col]:0)
// mode 2: v = (v + p1[b*256+col]) * p2[b*4096+row]
__global__ __launch_bounds__(256) void gemm_nt(
    const u16* __restrict__ A, const u16* __restrict__ B, u16* __restrict__ out,
    int K, int lda, int ldb, long sAb, long sBb, long sOb, long sR, long sC,
    int mode, const float* __restrict__ p1, const float* __restrict__ p2)
{
  __shared__ __align__(16) u16 As[128 * 32];
  __shared__ __align__(16) u16 Bs[128 * 32];
  int b = blockIdx.z;
  long i0 = (long)blockIdx.y * 128;
  long j0 = (long)blockIdx.x * 128;
  const u16* Ab = A + b * sAb + i0 * lda;
  const u16* Bb = B + b * sBb + j0 * ldb;
  int t = threadIdx.x, wave = t >> 6, lane = t & 63;
  int wi = (wave >> 1) * 64, wj = (wave & 1) * 64;
  int li = lane & 15, quad = lane >> 4;
  int qs = (lane & 3) ^ ((lane >> 3) & 3);   // swizzled source column (stage)
  int qx = quad ^ ((lane >> 1) & 3);         // swizzled quad-slot (read)
  f32x4 acc[4][4];
#pragma unroll
  for (int i = 0; i < 4; i++)
#pragma unroll
    for (int j = 0; j < 4; j++) acc[i][j] = (f32x4){0.f, 0.f, 0.f, 0.f};

  for (int k0 = 0; k0 < K; k0 += 32) {
#pragma unroll
    for (int h = 0; h < 2; h++) {
      int chunk = wave * 128 + h * 64 + lane;
      int r = chunk >> 2;
      ASYNC16(Ab + (long)r * lda + k0 + qs * 8, &As[(wave * 128 + h * 64) * 8]);
      ASYNC16(Bb + (long)r * ldb + k0 + qs * 8, &Bs[(wave * 128 + h * 64) * 8]);
    }
    __syncthreads();
    short8 af[4], bf[4];
#pragma unroll
    for (int s = 0; s < 4; s++) af[s] = *(const short8*)&As[(wi + s * 16 + li) * 32 + qx * 8];
#pragma unroll
    for (int s = 0; s < 4; s++) bf[s] = *(const short8*)&Bs[(wj + s * 16 + li) * 32 + qx * 8];
#pragma unroll
    for (int si = 0; si < 4; si++)
#pragma unroll
      for (int sj = 0; sj < 4; sj++)
        acc[si][sj] = __builtin_amdgcn_mfma_f32_16x16x32_bf16(af[si], bf[sj], acc[si][sj], 0, 0, 0);
    __syncthreads();
  }

#pragma unroll
  for (int si = 0; si < 4; si++)
#pragma unroll
    for (int sj = 0; sj < 4; sj++) {
      long col = j0 + wj + sj * 16 + li;
#pragma unroll
      for (int r = 0; r < 4; r++) {
        long row = i0 + wi + si * 16 + quad * 4 + r;
        float v = acc[si][sj][r];
        if (mode == 0) {
          if (p1) v += p1[row];
          if (p2) v += p2[col];
        } else {
          v = (v + p1[b * 256 + col]) * p2[b * 4096 + row];
        }
        out[b * sOb + row * sR + col * sC] = f2b(v);
      }
    }
}

// ---------------- kv split-n GEMM: part[sp][b][cv][ck] f32 (T2 swizzle) ----------------
__global__ __launch_bounds__(256) void gemm_kv(
    const u16* __restrict__ KV, float* __restrict__ part)
{
  __shared__ __align__(16) u16 As[128 * 32];
  __shared__ __align__(16) u16 Bs[128 * 32];
  int z = blockIdx.z;
  int b = z & 7, sp = z >> 3;
  long i0 = (long)blockIdx.y * 128;   // ck
  long j0 = (long)blockIdx.x * 128;   // cv
  const u16* Ab = KV + (long)b * 2 * NB + i0 * 4096;        // K rows
  const u16* Bb = KV + (long)b * 2 * NB + NB + j0 * 4096;   // V rows
  int t = threadIdx.x, wave = t >> 6, lane = t & 63;
  int wi = (wave >> 1) * 64, wj = (wave & 1) * 64;
  int li = lane & 15, quad = lane >> 4;
  int qs = (lane & 3) ^ ((lane >> 3) & 3);
  int qx = quad ^ ((lane >> 1) & 3);
  f32x4 acc[4][4];
#pragma unroll
  for (int i = 0; i < 4; i++)
#pragma unroll
    for (int j = 0; j < 4; j++) acc[i][j] = (f32x4){0.f, 0.f, 0.f, 0.f};

  int kend = sp * 512 + 512;
  for (int k0 = sp * 512; k0 < kend; k0 += 32) {
#pragma unroll
    for (int h = 0; h < 2; h++) {
      int chunk = wave * 128 + h * 64 + lane;
      int r = chunk >> 2;
      ASYNC16(Ab + (long)r * 4096 + k0 + qs * 8, &As[(wave * 128 + h * 64) * 8]);
      ASYNC16(Bb + (long)r * 4096 + k0 + qs * 8, &Bs[(wave * 128 + h * 64) * 8]);
    }
    __syncthreads();
    short8 af[4], bf[4];
#pragma unroll
    for (int s = 0; s < 4; s++) af[s] = *(const short8*)&As[(wi + s * 16 + li) * 32 + qx * 8];
#pragma unroll
    for (int s = 0; s < 4; s++) bf[s] = *(const short8*)&Bs[(wj + s * 16 + li) * 32 + qx * 8];
#pragma unroll
    for (int si = 0; si < 4; si++)
#pragma unroll
      for (int sj = 0; sj < 4; sj++)
        acc[si][sj] = __builtin_amdgcn_mfma_f32_16x16x32_bf16(af[si], bf[sj], acc[si][sj], 0, 0, 0);
    __syncthreads();
  }

  float* outp = part + ((long)sp * 8 + b) * 65536;
#pragma unroll
  for (int si = 0; si < 4; si++)
#pragma unroll
    for (int sj = 0; sj < 4; sj++) {
      long col = j0 + wj + sj * 16 + li;   // cv
#pragma unroll
      for (int r = 0; r < 4; r++) {
        long row = i0 + wi + si * 16 + quad * 4 + r;  // ck
        outp[col * 256 + row] = acc[si][sj][r];
      }
    }
}

__global__ __launch_bounds__(256) void reduce_kv(
    const float* __restrict__ part, u16* __restrict__ kvT)
{
  int g = blockIdx.x * 256 + threadIdx.x;  // 524288
  float s = 0.f;
#pragma unroll
  for (int sp = 0; sp < 8; sp++) s += part[(long)sp * 524288 + g];
  kvT[g] = f2b(s);
}

// ---------------- normalize Qt rows ----------------
__global__ __launch_bounds__(256) void normQ(u16* __restrict__ Qt)
{
  int row = blockIdx.x * 4 + (threadIdx.x >> 6);
  int lane = threadIdx.x & 63;
  u16* p = Qt + (long)row * 256 + lane * 4;
  us4v v = *(const us4v*)p;
  float f0 = b2f(v[0]), f1 = b2f(v[1]), f2 = b2f(v[2]), f3 = b2f(v[3]);
  float s = f0 * f0 + f1 * f1 + f2 * f2 + f3 * f3;
#pragma unroll
  for (int m = 32; m; m >>= 1) s += __shfl_xor(s, m, 64);
  float r = 1.0f / sqrtf(s);
  us4v o;
  o[0] = f2b(f0 * r); o[1] = f2b(f1 * r); o[2] = f2b(f2 * r); o[3] = f2b(f3 * r);
  *(us4v*)p = o;
}

// ---------------- K column sumsq -> rsqK[b][n] ----------------
__global__ __launch_bounds__(256) void sumsqK(
    const u16* __restrict__ KV, float* __restrict__ rsqK)
{
  __shared__ float red[8][132];
  int b = blockIdx.x >> 5, nc = blockIdx.x & 31;
  int n0 = nc * 128;
  int t = threadIdx.x;
  int nn = (t & 31) * 4, cg = t >> 5;
  const u16* base = KV + (long)b * 2 * NB;
  float s0 = 0.f, s1 = 0.f, s2 = 0.f, s3 = 0.f;
  for (int st = 0; st < 32; st++) {
    int c = cg + st * 8;
    us4v v = *(const us4v*)(base + (long)c * 4096 + n0 + nn);
    float a = b2f(v[0]), bb = b2f(v[1]), cc = b2f(v[2]), dd = b2f(v[3]);
    s0 = fmaf(a, a, s0); s1 = fmaf(bb, bb, s1);
    s2 = fmaf(cc, cc, s2); s3 = fmaf(dd, dd, s3);
  }
  red[cg][nn] = s0; red[cg][nn + 1] = s1; red[cg][nn + 2] = s2; red[cg][nn + 3] = s3;
  __syncthreads();
  if (t < 128) {
    float s = 0.f;
#pragma unroll
    for (int g = 0; g < 8; g++) s += red[g][t];
    rsqK[b * 4096 + n0 + t] = 1.0f / sqrtf(s);
  }
}

// ---------------- scale K rows by rsqK + ksum; V rows -> vsum ----------------
__global__ __launch_bounds__(256) void scale_sums(
    u16* __restrict__ KV, const float* __restrict__ rsqK,
    float* __restrict__ ksum, float* __restrict__ vsum)
{
  int z = blockIdx.x;
  int isV = z >> 11, rem = z & 2047, b = rem >> 8, c = rem & 255;
  u16* row = KV + (long)b * 2 * NB + (long)isV * NB + (long)c * 4096;
  const float* rq = rsqK + b * 4096;
  int t = threadIdx.x;
  float s = 0.f;
  short8 v0 = *(const short8*)&row[t * 16];
  short8 v1 = *(const short8*)&row[t * 16 + 8];
  if (!isV) {
    short8 o0, o1;
#pragma unroll
    for (int e = 0; e < 8; e++) {
      float a = b2f((u16)v0[e]) * rq[t * 16 + e];
      float bb = b2f((u16)v1[e]) * rq[t * 16 + 8 + e];
      s += a + bb;
      o0[e] = (short)f2b(a); o1[e] = (short)f2b(bb);
    }
    *(short8*)&row[t * 16] = o0;
    *(short8*)&row[t * 16 + 8] = o1;
  } else {
#pragma unroll
    for (int e = 0; e < 8; e++) s += b2f((u16)v0[e]) + b2f((u16)v1[e]);
  }
#pragma unroll
  for (int off = 32; off; off >>= 1) s += __shfl_down(s, off, 64);
  __shared__ float red[4];
  if ((t & 63) == 0) red[t >> 6] = s;
  __syncthreads();
  if (t == 0)
    (isV ? vsum : ksum)[b * 256 + c] = red[0] + red[1] + red[2] + red[3];
}

// ---------------- den[b][n] = 1/(4096 + Qn[n,:].ksum + eps) ----------------
__global__ __launch_bounds__(256) void denom_k(
    const u16* __restrict__ Qt, const float* __restrict__ ksum,
    float* __restrict__ den)
{
  int row = blockIdx.x * 4 + (threadIdx.x >> 6);
  int lane = threadIdx.x & 63;
  int b = row >> 12;
  us4v v = *(const us4v*)(Qt + (long)row * 256 + lane * 4);
  float4 ks = *(const float4*)&ksum[b * 256 + lane * 4];
  float s = b2f(v[0]) * ks.x + b2f(v[1]) * ks.y + b2f(v[2]) * ks.z + b2f(v[3]) * ks.w;
#pragma unroll
  for (int m = 32; m; m >>= 1) s += __shfl_xor(s, m, 64);
  if (lane == 0) den[row] = 1.0f / (4096.0f + s + 1e-6f);
}

// ---------------- conv3x3 implicit GEMM: 64x128 tile, depth-3 counted-vmcnt, T2 swizzle ----------------
// out[m][n] = sum_{d,c} W[m][d*256+c] * img[n + delta(d)][c], K = 2304 (72 steps).
// Triple-buffered LDS (3 x [A 64x32 | B 128x32] = 36KB). Per K-step per thread:
// exactly 3 ASYNC16 (1 A-granule + 2 B-granules); OOB halo granules load from a
// zero page so vmcnt counts are deterministic. Main loop: s_waitcnt vmcnt(6)
// (2 stages in flight) + raw s_barrier; stage ks+3 issued after compute of ks.
// LDS quad-slot swizzled (qs stage / qx read) -> fragment reads 2-way = free.
// Grid 1024 (= 4 blocks/CU); lin&7 -> batch == XCD (round-robin dispatch).
// mode 0: out16[b][n][256] = acc + corrT[n][m]   (us4v store, f32x4 corr read)
// mode 1: out32[b][m][4096] = (acc + cb[m])*x + x
__global__ __launch_bounds__(256, 4) void conv_gemm(
    const u16* __restrict__ inT, const u16* __restrict__ wr,
    const float* __restrict__ cb, const float* __restrict__ xres,
    const float* __restrict__ zbuf,
    u16* __restrict__ out16, float* __restrict__ out32, int mode)
{
  __shared__ __align__(16) u16 S[3 * 6144];   // per buf: A[64][32] @0, B[128][32] @2048

  int lin = blockIdx.x;            // 1024 blocks
  int b   = lin & 7;               // == XCD id under round-robin dispatch
  int idx = lin >> 3;              // 0..127 ; m fastest (B-tile reuse across m)
  int i0  = (idx & 3) * 64;        // m tile
  int n0  = (idx >> 2) * 128;      // n tile = 2 image rows

  int t = threadIdx.x, wave = t >> 6, lane = t & 63;
  int wi = (wave >> 1) * 32, wj = (wave & 1) * 64;
  int li = lane & 15, quad = lane >> 4;
  int qs = (t & 3) ^ ((t >> 3) & 3);         // swizzled source column (stage)
  int qx = quad ^ ((lane >> 1) & 3);         // swizzled quad-slot (read)
  const u16* inb = inT + (long)b * NB;

  // per-thread staging addresses (granule = 16B = 8 ch), source pre-swizzled
  const u16* Ag  = wr  + (long)(i0 + (t >> 2)) * 2304 + qs * 8;
  const u16* Bg0 = inb + (long)(n0 + (t >> 2)) * 256 + qs * 8;
  const u16* Bg1 = Bg0 + 64 * 256;
  const u16* zp  = (const u16*)zbuf + qs * 8;
  int yb0 = n0 >> 6, yb1 = yb0 + 1, xb = t >> 2;   // xb = x coord (0..63)

  f32x4 acc[2][4];
#pragma unroll
  for (int i = 0; i < 2; i++)
#pragma unroll
    for (int j = 0; j < 4; j++) acc[i][j] = (f32x4){0.f, 0.f, 0.f, 0.f};

  // stage K-step ks into buffer buf: ALWAYS 3 loads per thread.
  auto STAGE = [&](int ks, int buf) {
    int d = ks >> 3;
    int dy = d / 3 - 1, dx = d - (d / 3) * 3 - 1;
    long shift = (long)(dy * 64 + dx) * 256 + (ks & 7) * 32;
    u16* base = &S[buf * 6144];
    ASYNC16(Ag + (long)ks * 32, base + wave * 512);
    const u16* s0 = ((unsigned)(yb0 + dy) < 64u && (unsigned)(xb + dx) < 64u)
                    ? Bg0 + shift : zp;
    const u16* s1 = ((unsigned)(yb1 + dy) < 64u && (unsigned)(xb + dx) < 64u)
                    ? Bg1 + shift : zp;
    ASYNC16(s0, base + 2048 + wave * 512);
    ASYNC16(s1, base + 4096 + wave * 512);
  };

  auto COMPUTE = [&](int buf) {
    const u16* as = &S[buf * 6144];
    const u16* bs = as + 2048;
    short8 af[2], bf[4];
#pragma unroll
    for (int s = 0; s < 2; s++) af[s] = *(const short8*)&as[(wi + s * 16 + li) * 32 + qx * 8];
#pragma unroll
    for (int s = 0; s < 4; s++) bf[s] = *(const short8*)&bs[(wj + s * 16 + li) * 32 + qx * 8];
#pragma unroll
    for (int si = 0; si < 2; si++)
#pragma unroll
      for (int sj = 0; sj < 4; sj++)
        acc[si][sj] = __builtin_amdgcn_mfma_f32_16x16x32_bf16(af[si], bf[sj], acc[si][sj], 0, 0, 0);
  };

  STAGE(0, 0); STAGE(1, 1); STAGE(2, 2);   // 9 loads in flight

  int cur = 0;
#pragma unroll 1
  for (int ks = 0; ks < 69; ks++) {
    asm volatile("s_waitcnt vmcnt(6)" ::: "memory");   // stage ks landed (mine)
    __builtin_amdgcn_s_barrier();                      // everyone's landed
    COMPUTE(cur);
    __builtin_amdgcn_s_barrier();                      // all reads of buf done
    STAGE(ks + 3, cur);                                // overwrite freed buffer
    cur = (cur == 2) ? 0 : cur + 1;
  }
  // ks = 69: stages 70,71 in flight (6)
  asm volatile("s_waitcnt vmcnt(6)" ::: "memory");
  __builtin_amdgcn_s_barrier();
  COMPUTE(cur);
  cur = (cur == 2) ? 0 : cur + 1;
  // ks = 70: stage 71 in flight (3)
  asm volatile("s_waitcnt vmcnt(3)" ::: "memory");
  __builtin_amdgcn_s_barrier();
  COMPUTE(cur);
  cur = (cur == 2) ? 0 : cur + 1;
  // ks = 71
  asm volatile("s_waitcnt vmcnt(0)" ::: "memory");
  __builtin_amdgcn_s_barrier();
  COMPUTE(cur);

#pragma unroll
  for (int si = 0; si < 2; si++)
#pragma unroll
    for (int sj = 0; sj < 4; sj++) {
      int col = n0 + wj + sj * 16 + li;              // n
      int row0 = i0 + wi + si * 16 + quad * 4;       // m base (multiple of 4)
      if (mode == 0) {
        f32x4 c4 = *(const f32x4*)&cb[(long)col * 256 + row0];
        us4v o;
#pragma unroll
        for (int r = 0; r < 4; r++) o[r] = f2b(acc[si][sj][r] + c4[r]);
        *(us4v*)&out16[(long)b * NB + (long)col * 256 + row0] = o;
      } else {
#pragma unroll
        for (int r = 0; r < 4; r++) {
          int row = row0 + r;
          float v = acc[si][sj][r] + cb[row];
          long a = (long)b * NB + (long)row * 4096 + col;
          float xv = xres[a];
          out32[a] = fmaf(v, xv, xv);
        }
      }
    }
}

// ---------------- host ----------------
extern "C" void kernel_launch(void* const* d_in, const int* in_sizes, int n_in,
                              void* d_out, int out_size, void* d_ws, size_t ws_size,
                              hipStream_t stream)
{
  const float* x   = (const float*)d_in[0];
  const float* qw  = (const float*)d_in[1];
  const float* qb  = (const float*)d_in[2];
  const float* kw  = (const float*)d_in[3];
  const float* kb  = (const float*)d_in[4];
  const float* vw  = (const float*)d_in[5];
  const float* vb  = (const float*)d_in[6];
  const float* rw  = (const float*)d_in[7];
  const float* rb  = (const float*)d_in[8];
  const float* c1w = (const float*)d_in[9];
  const float* c1b = (const float*)d_in[10];
  const float* c2w = (const float*)d_in[11];
  const float* c2b = (const float*)d_in[12];

  // ws layout (u16 units)
  u16* U     = (u16*)d_ws;
  u16* xT16  = U;                     // 8388608 ; later wvT16
  u16* Qt16  = U + 8388608;           // 8388608 ; later h1T16
  u16* KV16  = U + 16777216;          // 16777216 (K rows 0-255, V rows 256-511 per b)
  u16* wr2   = U + 33554432;          // 589824
  u16* kvT16 = U + 34144256;          // 524288
  float* Fws = (float*)(U + 34668544);
  float* ksum = Fws;                  // 2048
  float* vsum = Fws + 2048;           // 2048
  float* zbuf = Fws + 4096;           // 64 (zero page for conv OOB loads)

  // d_out scratch (all dead before conv2 writes d_out; conv2 reads NOTHING here)
  char* ob = (char*)d_out;
  float* kvpart = (float*)(ob + 0);           // 16777216 B
  float* den    = (float*)(ob + 16777216);    // 131072
  float* rsqK   = (float*)(ob + 16908288);    // 131072
  float* corr   = (float*)(ob + 17039360);    // 4194304  (layout [n][m])
  u16*   w1p16  = (u16*)(ob + 21233664);      // 1179648
  u16*   wr1    = (u16*)(ob + 22413312);      // 1179648
  float* T      = (float*)(ob + 23592960);    // 36864
  u16*   rwT16  = (u16*)(ob + 23629824);      // 131072
  u16*   qw16   = (u16*)(ob + 23760896);      // 131072
  u16*   kvw16  = (u16*)(ob + 23891968);      // 262144
  float* kvbias = (float*)(ob + 24154112);    // 2048
  float* outF   = (float*)d_out;

  u16* wvT16 = xT16;
  u16* h1T16 = Qt16;

  dim3 blk(256);

  prep1<<<5633, blk, 0, stream>>>(qw, kw, vw, rw, c1w, c2w, kb, vb,
                                  qw16, kvw16, rwT16, wr1, wr2, kvbias, zbuf);
  prep_T<<<9, blk, 0, stream>>>(c1w, rb, T);
  corr_k<<<4096, blk, 0, stream>>>(T, c1b, corr);
  transposeX<<<dim3(64, 4, 8), blk, 0, stream>>>(x, xT16);

  // w1' = wr1 @ rwT : folds rw into conv1 weights, layout [m][d*256+cv]
  gemm_nt<<<dim3(2, 18, 1), blk, 0, stream>>>(wr1, rwT16, w1p16,
      256, 256, 256, 0L, 0L, 0L, 256L, 1L, 0, nullptr, nullptr);
  // Qt[b][n][ck] = xT @ qw^T + qb
  gemm_nt<<<dim3(2, 32, 8), blk, 0, stream>>>(xT16, qw16, Qt16,
      256, 256, 256, NB, 0L, NB, 256L, 1L, 0, nullptr, qb);
  // KV[b][cq][n] = [kw|vw] @ x + [kb|vb]
  gemm_nt<<<dim3(32, 4, 8), blk, 0, stream>>>(kvw16, xT16, KV16,
      256, 256, 256, 0L, NB, 2 * NB, 4096L, 1L, 0, kvbias, nullptr);

  normQ<<<8192, blk, 0, stream>>>(Qt16);
  sumsqK<<<256, blk, 0, stream>>>(KV16, rsqK);
  scale_sums<<<4096, blk, 0, stream>>>(KV16, rsqK, ksum, vsum);
  denom_k<<<8192, blk, 0, stream>>>(Qt16, ksum, den);

  gemm_kv<<<dim3(2, 2, 64), blk, 0, stream>>>(KV16, kvpart);
  reduce_kv<<<2048, blk, 0, stream>>>(kvpart, kvT16);

  // wvT[b][n][cv] = (Qt @ kv + vsum)*den   (coalesced stores)
  gemm_nt<<<dim3(2, 32, 8), blk, 0, stream>>>(Qt16, kvT16, wvT16,
      256, 256, 256, NB, 65536L, NB, 256L, 1L, 2, vsum, den);

  conv_gemm<<<1024, blk, 0, stream>>>(wvT16, w1p16, corr, nullptr, zbuf,
                                      h1T16, nullptr, 0);
  conv_gemm<<<1024, blk, 0, stream>>>(h1T16, wr2, c2b, x, zbuf,
                                      nullptr, outF, 1);
}

// Round 5
// 393.391 us; speedup vs baseline: 1.0659x; 1.0322x over previous
//
#include <hip/hip_runtime.h>
#include <math.h>

// HydraAttention R9 — attack the invisible mid-tier (conv is at the 2-phase
// structural ceiling, 535 TF; m233/m252 say only a full 8-phase port moves it).
//
// R8 post-mortem: T2 swizzle zeroed SQ_LDS_BANK_CONFLICT (7.08M -> 0) but conv
// time -2.7% only -> conflicts weren't on the critical path (m252 gate).
// Total is 406us; convs are 145us; ~261us sits in dispatches we can't see
// (top-5 only). Known defects there, fixed this round:
//   1. gemm_nt (x4 launches): still __syncthreads full-vmcnt-drain per K-step
//      (R6's flaw) -> double-buffer + counted s_waitcnt vmcnt(4) + raw
//      s_barrier (proven R7 pattern).
//   2. gemm_kv: 1 block/CU, same drain flaw -> same dbuf counted pipeline.
//   3. sumsqK: grid 256 = 1 block/CU -> 512 blocks (64-col chunks).
//   4. normQ + denom_k both stream Qt 16MB -> fused normQden (one pass,
//      saves 16MB read + a launch), placed after scale_sums.
// conv_gemm unchanged from R8 (triple-buffer vmcnt(6), T2-swizzled, passed).

typedef unsigned short u16;
typedef __attribute__((ext_vector_type(8))) short short8;
typedef __attribute__((ext_vector_type(4))) float f32x4;
typedef __attribute__((ext_vector_type(4))) unsigned short us4v;

#define ASYNC16(g, l) __builtin_amdgcn_global_load_lds( \
    (const __attribute__((address_space(1))) unsigned int*)(g), \
    (__attribute__((address_space(3))) unsigned int*)(l), 16, 0, 0)

static __device__ __forceinline__ float b2f(u16 h) {
  unsigned int u = ((unsigned int)h) << 16;
  return __builtin_bit_cast(float, u);
}
static __device__ __forceinline__ u16 f2b(float f) {
  unsigned int u = __builtin_bit_cast(unsigned int, f);
  u += 0x7fffu + ((u >> 16) & 1u);
  return (u16)(u >> 16);
}

#define NB 1048576L

// ---------------- prep1: weight converts/reorders + kvbias + zero page ----------------
__global__ __launch_bounds__(256) void prep1(
    const float* __restrict__ qw, const float* __restrict__ kw,
    const float* __restrict__ vw, const float* __restrict__ rw,
    const float* __restrict__ c1w, const float* __restrict__ c2w,
    const float* __restrict__ kb, const float* __restrict__ vb,
    u16* __restrict__ qw16, u16* __restrict__ kvw16, u16* __restrict__ rwT16,
    u16* __restrict__ wr1, u16* __restrict__ wr2,
    float* __restrict__ kvbias, float* __restrict__ zbuf)
{
  if (blockIdx.x == 5632) {
    int t = threadIdx.x;
    if (t < 256) { kvbias[t] = kb[t]; kvbias[t + 256] = vb[t]; }
    if (t < 64) zbuf[t] = 0.f;
    return;
  }
  long g = (long)blockIdx.x * 256 + threadIdx.x;
  if (g < 65536) {
    qw16[g] = f2b(qw[g]);
  } else if (g < 196608) {
    long e = g - 65536;
    kvw16[e] = f2b(e < 65536 ? kw[e] : vw[e - 65536]);
  } else if (g < 262144) {
    long e = g - 196608;
    int cv = e >> 8, co = e & 255;
    rwT16[e] = f2b(rw[co * 256 + cv]);
  } else if (g < 851968) {
    long e = g - 262144;
    int m = e / 2304, r = e - m * 2304;
    int d = r >> 8, c = r & 255;
    wr1[e] = f2b(c1w[m * 2304 + c * 9 + d]);
  } else {
    long e = g - 851968;
    int m = e / 2304, r = e - m * 2304;
    int d = r >> 8, c = r & 255;
    wr2[e] = f2b(c2w[m * 2304 + c * 9 + d]);
  }
}

// T[m*9+t] = sum_co c1w[m][co][t]*rb[co]
__global__ __launch_bounds__(256) void prep_T(
    const float* __restrict__ c1w, const float* __restrict__ rb, float* __restrict__ T)
{
  int e = blockIdx.x * 256 + threadIdx.x;   // 2304
  int m = e / 9, d = e - m * 9;
  float s = 0.f;
  for (int co = 0; co < 256; co++) s += c1w[m * 2304 + co * 9 + d] * rb[co];
  T[e] = s;
}

// corr[p][m] = c1b[m] + sum_{t valid at p} T[m][t]   (TRANSPOSED layout [n][m])
__global__ __launch_bounds__(256) void corr_k(
    const float* __restrict__ T, const float* __restrict__ c1b, float* __restrict__ corr)
{
  int e = blockIdx.x * 256 + threadIdx.x;   // 1048576
  int m = e & 255, p = e >> 8;
  int y = p >> 6, xx = p & 63;
  float s = c1b[m];
#pragma unroll
  for (int d = 0; d < 9; d++) {
    int dy = d / 3 - 1, dx = d - (d / 3) * 3 - 1;
    if ((unsigned)(y + dy) < 64u && (unsigned)(xx + dx) < 64u) s += T[m * 9 + d];
  }
  corr[e] = s;                              // corr[p*256 + m], coalesced
}

// ---------------- x [b][c][n] f32 -> xT16 [b][n][c] bf16 ----------------
__global__ __launch_bounds__(256) void transposeX(
    const float* __restrict__ x, u16* __restrict__ xT)
{
  __shared__ float T[64][65];
  int n0 = blockIdx.x * 64, c0 = blockIdx.y * 64, b = blockIdx.z;
  int t = threadIdx.x;
#pragma unroll
  for (int i = 0; i < 4; i++) {
    int c = (t >> 4) + i * 16, nn = (t & 15) * 4;
    float4 v = *(const float4*)&x[(long)b * NB + (long)(c0 + c) * 4096 + n0 + nn];
    T[c][nn] = v.x; T[c][nn + 1] = v.y; T[c][nn + 2] = v.z; T[c][nn + 3] = v.w;
  }
  __syncthreads();
#pragma unroll
  for (int i = 0; i < 4; i++) {
    int n = (t >> 4) + i * 16, cc = (t & 15) * 4;
    us4v o;
#pragma unroll
    for (int e = 0; e < 4; e++) o[e] = f2b(T[cc + e][n]);
    *(us4v*)&xT[(long)b * NB + (long)(n0 + n) * 256 + c0 + cc] = o;
  }
}

// ---------------- generic NT bf16 MFMA GEMM: dbuf + counted vmcnt + T2 swizzle ----------------
// D[i][j] = sum_k A[i][k]*B[j][k]
// mode 0: v += (p1?p1[row]:0) + (p2?p2[col]:0)
// mode 2: v = (v + p1[b*256+col]) * p2[b*4096+row]
__global__ __launch_bounds__(256) void gemm_nt(
    const u16* __restrict__ A, const u16* __restrict__ B, u16* __restrict__ out,
    int K, int lda, int ldb, long sAb, long sBb, long sOb, long sR, long sC,
    int mode, const float* __restrict__ p1, const float* __restrict__ p2)
{
  __shared__ __align__(16) u16 As[2][128 * 32];
  __shared__ __align__(16) u16 Bs[2][128 * 32];
  int b = blockIdx.z;
  long i0 = (long)blockIdx.y * 128;
  long j0 = (long)blockIdx.x * 128;
  const u16* Ab = A + b * sAb + i0 * lda;
  const u16* Bb = B + b * sBb + j0 * ldb;
  int t = threadIdx.x, wave = t >> 6, lane = t & 63;
  int wi = (wave >> 1) * 64, wj = (wave & 1) * 64;
  int li = lane & 15, quad = lane >> 4;
  int qs = (lane & 3) ^ ((lane >> 3) & 3);   // swizzled source column (stage)
  int qx = quad ^ ((lane >> 1) & 3);         // swizzled quad-slot (read)
  int r0 = (wave * 128 + lane) >> 2;         // staging rows (h=0,1)
  int r1 = (wave * 128 + 64 + lane) >> 2;
  f32x4 acc[4][4];
#pragma unroll
  for (int i = 0; i < 4; i++)
#pragma unroll
    for (int j = 0; j < 4; j++) acc[i][j] = (f32x4){0.f, 0.f, 0.f, 0.f};

  // 4 ASYNC16 per thread per stage
  auto STAGE = [&](int kc, int buf) {
    int k0 = kc * 32;
    ASYNC16(Ab + (long)r0 * lda + k0 + qs * 8, &As[buf][(wave * 128) * 8]);
    ASYNC16(Bb + (long)r0 * ldb + k0 + qs * 8, &Bs[buf][(wave * 128) * 8]);
    ASYNC16(Ab + (long)r1 * lda + k0 + qs * 8, &As[buf][(wave * 128 + 64) * 8]);
    ASYNC16(Bb + (long)r1 * ldb + k0 + qs * 8, &Bs[buf][(wave * 128 + 64) * 8]);
  };

  int nk = K >> 5, cur = 0;
  STAGE(0, 0);
#pragma unroll 1
  for (int kc = 0; kc < nk; kc++) {
    if (kc + 1 < nk) {
      STAGE(kc + 1, cur ^ 1);
      asm volatile("s_waitcnt vmcnt(4)" ::: "memory");   // stage kc landed
    } else {
      asm volatile("s_waitcnt vmcnt(0)" ::: "memory");
    }
    __builtin_amdgcn_s_barrier();
    const u16* as = &As[cur][0];
    const u16* bs = &Bs[cur][0];
    short8 af[4], bf[4];
#pragma unroll
    for (int s = 0; s < 4; s++) af[s] = *(const short8*)&as[(wi + s * 16 + li) * 32 + qx * 8];
#pragma unroll
    for (int s = 0; s < 4; s++) bf[s] = *(const short8*)&bs[(wj + s * 16 + li) * 32 + qx * 8];
#pragma unroll
    for (int si = 0; si < 4; si++)
#pragma unroll
      for (int sj = 0; sj < 4; sj++)
        acc[si][sj] = __builtin_amdgcn_mfma_f32_16x16x32_bf16(af[si], bf[sj], acc[si][sj], 0, 0, 0);
    __builtin_amdgcn_s_barrier();                        // reads of cur done
    cur ^= 1;
  }

#pragma unroll
  for (int si = 0; si < 4; si++)
#pragma unroll
    for (int sj = 0; sj < 4; sj++) {
      long col = j0 + wj + sj * 16 + li;
#pragma unroll
      for (int r = 0; r < 4; r++) {
        long row = i0 + wi + si * 16 + quad * 4 + r;
        float v = acc[si][sj][r];
        if (mode == 0) {
          if (p1) v += p1[row];
          if (p2) v += p2[col];
        } else {
          v = (v + p1[b * 256 + col]) * p2[b * 4096 + row];
        }
        out[b * sOb + row * sR + col * sC] = f2b(v);
      }
    }
}

// ---------------- kv split-n GEMM: dbuf + counted vmcnt + T2 swizzle ----------------
__global__ __launch_bounds__(256) void gemm_kv(
    const u16* __restrict__ KV, float* __restrict__ part)
{
  __shared__ __align__(16) u16 As[2][128 * 32];
  __shared__ __align__(16) u16 Bs[2][128 * 32];
  int z = blockIdx.z;
  int b = z & 7, sp = z >> 3;
  long i0 = (long)blockIdx.y * 128;   // ck
  long j0 = (long)blockIdx.x * 128;   // cv
  const u16* Ab = KV + (long)b * 2 * NB + i0 * 4096;        // K rows
  const u16* Bb = KV + (long)b * 2 * NB + NB + j0 * 4096;   // V rows
  int t = threadIdx.x, wave = t >> 6, lane = t & 63;
  int wi = (wave >> 1) * 64, wj = (wave & 1) * 64;
  int li = lane & 15, quad = lane >> 4;
  int qs = (lane & 3) ^ ((lane >> 3) & 3);
  int qx = quad ^ ((lane >> 1) & 3);
  int r0 = (wave * 128 + lane) >> 2;
  int r1 = (wave * 128 + 64 + lane) >> 2;
  f32x4 acc[4][4];
#pragma unroll
  for (int i = 0; i < 4; i++)
#pragma unroll
    for (int j = 0; j < 4; j++) acc[i][j] = (f32x4){0.f, 0.f, 0.f, 0.f};

  auto STAGE = [&](int kc, int buf) {
    int k0 = sp * 512 + kc * 32;
    ASYNC16(Ab + (long)r0 * 4096 + k0 + qs * 8, &As[buf][(wave * 128) * 8]);
    ASYNC16(Bb + (long)r0 * 4096 + k0 + qs * 8, &Bs[buf][(wave * 128) * 8]);
    ASYNC16(Ab + (long)r1 * 4096 + k0 + qs * 8, &As[buf][(wave * 128 + 64) * 8]);
    ASYNC16(Bb + (long)r1 * 4096 + k0 + qs * 8, &Bs[buf][(wave * 128 + 64) * 8]);
  };

  int cur = 0;
  STAGE(0, 0);
#pragma unroll 1
  for (int kc = 0; kc < 16; kc++) {
    if (kc + 1 < 16) {
      STAGE(kc + 1, cur ^ 1);
      asm volatile("s_waitcnt vmcnt(4)" ::: "memory");
    } else {
      asm volatile("s_waitcnt vmcnt(0)" ::: "memory");
    }
    __builtin_amdgcn_s_barrier();
    const u16* as = &As[cur][0];
    const u16* bs = &Bs[cur][0];
    short8 af[4], bf[4];
#pragma unroll
    for (int s = 0; s < 4; s++) af[s] = *(const short8*)&as[(wi + s * 16 + li) * 32 + qx * 8];
#pragma unroll
    for (int s = 0; s < 4; s++) bf[s] = *(const short8*)&bs[(wj + s * 16 + li) * 32 + qx * 8];
#pragma unroll
    for (int si = 0; si < 4; si++)
#pragma unroll
      for (int sj = 0; sj < 4; sj++)
        acc[si][sj] = __builtin_amdgcn_mfma_f32_16x16x32_bf16(af[si], bf[sj], acc[si][sj], 0, 0, 0);
    __builtin_amdgcn_s_barrier();
    cur ^= 1;
  }

  float* outp = part + ((long)sp * 8 + b) * 65536;
#pragma unroll
  for (int si = 0; si < 4; si++)
#pragma unroll
    for (int sj = 0; sj < 4; sj++) {
      long col = j0 + wj + sj * 16 + li;   // cv
#pragma unroll
      for (int r = 0; r < 4; r++) {
        long row = i0 + wi + si * 16 + quad * 4 + r;  // ck
        outp[col * 256 + row] = acc[si][sj][r];
      }
    }
}

__global__ __launch_bounds__(256) void reduce_kv(
    const float* __restrict__ part, u16* __restrict__ kvT)
{
  int g = blockIdx.x * 256 + threadIdx.x;  // 524288
  float s = 0.f;
#pragma unroll
  for (int sp = 0; sp < 8; sp++) s += part[(long)sp * 524288 + g];
  kvT[g] = f2b(s);
}

// ---------------- fused: normalize Qt rows + den[b][n] = 1/(4096 + Qn.ksum + eps) ----------------
__global__ __launch_bounds__(256) void normQden(
    u16* __restrict__ Qt, const float* __restrict__ ksum, float* __restrict__ den)
{
  int row = blockIdx.x * 4 + (threadIdx.x >> 6);
  int lane = threadIdx.x & 63;
  int b = row >> 12;
  u16* p = Qt + (long)row * 256 + lane * 4;
  us4v v = *(const us4v*)p;
  float f0 = b2f(v[0]), f1 = b2f(v[1]), f2 = b2f(v[2]), f3 = b2f(v[3]);
  float s = f0 * f0 + f1 * f1 + f2 * f2 + f3 * f3;
#pragma unroll
  for (int m = 32; m; m >>= 1) s += __shfl_xor(s, m, 64);
  float r = 1.0f / sqrtf(s);
  float o0 = f0 * r, o1 = f1 * r, o2 = f2 * r, o3 = f3 * r;
  us4v o;
  o[0] = f2b(o0); o[1] = f2b(o1); o[2] = f2b(o2); o[3] = f2b(o3);
  *(us4v*)p = o;
  float4 ks = *(const float4*)&ksum[b * 256 + lane * 4];
  float s2 = o0 * ks.x + o1 * ks.y + o2 * ks.z + o3 * ks.w;
#pragma unroll
  for (int m = 32; m; m >>= 1) s2 += __shfl_xor(s2, m, 64);
  if (lane == 0) den[row] = 1.0f / (4096.0f + s2 + 1e-6f);
}

// ---------------- K column sumsq -> rsqK[b][n] (512 blocks = 2/CU) ----------------
__global__ __launch_bounds__(256) void sumsqK(
    const u16* __restrict__ KV, float* __restrict__ rsqK)
{
  __shared__ float red[16][68];
  int b = blockIdx.x >> 6, nc = blockIdx.x & 63;
  int n0 = nc * 64;
  int t = threadIdx.x;
  int nn = (t & 15) * 4, cg = t >> 4;
  const u16* base = KV + (long)b * 2 * NB;
  float s0 = 0.f, s1 = 0.f, s2 = 0.f, s3 = 0.f;
  for (int st = 0; st < 16; st++) {
    int c = cg + st * 16;
    us4v v = *(const us4v*)(base + (long)c * 4096 + n0 + nn);
    float a = b2f(v[0]), bb = b2f(v[1]), cc = b2f(v[2]), dd = b2f(v[3]);
    s0 = fmaf(a, a, s0); s1 = fmaf(bb, bb, s1);
    s2 = fmaf(cc, cc, s2); s3 = fmaf(dd, dd, s3);
  }
  red[cg][nn] = s0; red[cg][nn + 1] = s1; red[cg][nn + 2] = s2; red[cg][nn + 3] = s3;
  __syncthreads();
  if (t < 64) {
    float s = 0.f;
#pragma unroll
    for (int g = 0; g < 16; g++) s += red[g][t];
    rsqK[b * 4096 + n0 + t] = 1.0f / sqrtf(s);
  }
}

// ---------------- scale K rows by rsqK + ksum; V rows -> vsum ----------------
__global__ __launch_bounds__(256) void scale_sums(
    u16* __restrict__ KV, const float* __restrict__ rsqK,
    float* __restrict__ ksum, float* __restrict__ vsum)
{
  int z = blockIdx.x;
  int isV = z >> 11, rem = z & 2047, b = rem >> 8, c = rem & 255;
  u16* row = KV + (long)b * 2 * NB + (long)isV * NB + (long)c * 4096;
  const float* rq = rsqK + b * 4096;
  int t = threadIdx.x;
  float s = 0.f;
  short8 v0 = *(const short8*)&row[t * 16];
  short8 v1 = *(const short8*)&row[t * 16 + 8];
  if (!isV) {
    short8 o0, o1;
#pragma unroll
    for (int e = 0; e < 8; e++) {
      float a = b2f((u16)v0[e]) * rq[t * 16 + e];
      float bb = b2f((u16)v1[e]) * rq[t * 16 + 8 + e];
      s += a + bb;
      o0[e] = (short)f2b(a); o1[e] = (short)f2b(bb);
    }
    *(short8*)&row[t * 16] = o0;
    *(short8*)&row[t * 16 + 8] = o1;
  } else {
#pragma unroll
    for (int e = 0; e < 8; e++) s += b2f((u16)v0[e]) + b2f((u16)v1[e]);
  }
#pragma unroll
  for (int off = 32; off; off >>= 1) s += __shfl_down(s, off, 64);
  __shared__ float red[4];
  if ((t & 63) == 0) red[t >> 6] = s;
  __syncthreads();
  if (t == 0)
    (isV ? vsum : ksum)[b * 256 + c] = red[0] + red[1] + red[2] + red[3];
}

// ---------------- conv3x3 implicit GEMM: 64x128 tile, depth-3 counted-vmcnt, T2 swizzle ----------------
// (unchanged from R8)
__global__ __launch_bounds__(256, 4) void conv_gemm(
    const u16* __restrict__ inT, const u16* __restrict__ wr,
    const float* __restrict__ cb, const float* __restrict__ xres,
    const float* __restrict__ zbuf,
    u16* __restrict__ out16, float* __restrict__ out32, int mode)
{
  __shared__ __align__(16) u16 S[3 * 6144];   // per buf: A[64][32] @0, B[128][32] @2048

  int lin = blockIdx.x;            // 1024 blocks
  int b   = lin & 7;               // == XCD id under round-robin dispatch
  int idx = lin >> 3;              // 0..127 ; m fastest (B-tile reuse across m)
  int i0  = (idx & 3) * 64;        // m tile
  int n0  = (idx >> 2) * 128;      // n tile = 2 image rows

  int t = threadIdx.x, wave = t >> 6, lane = t & 63;
  int wi = (wave >> 1) * 32, wj = (wave & 1) * 64;
  int li = lane & 15, quad = lane >> 4;
  int qs = (t & 3) ^ ((t >> 3) & 3);         // swizzled source column (stage)
  int qx = quad ^ ((lane >> 1) & 3);         // swizzled quad-slot (read)
  const u16* inb = inT + (long)b * NB;

  // per-thread staging addresses (granule = 16B = 8 ch), source pre-swizzled
  const u16* Ag  = wr  + (long)(i0 + (t >> 2)) * 2304 + qs * 8;
  const u16* Bg0 = inb + (long)(n0 + (t >> 2)) * 256 + qs * 8;
  const u16* Bg1 = Bg0 + 64 * 256;
  const u16* zp  = (const u16*)zbuf + qs * 8;
  int yb0 = n0 >> 6, yb1 = yb0 + 1, xb = t >> 2;   // xb = x coord (0..63)

  f32x4 acc[2][4];
#pragma unroll
  for (int i = 0; i < 2; i++)
#pragma unroll
    for (int j = 0; j < 4; j++) acc[i][j] = (f32x4){0.f, 0.f, 0.f, 0.f};

  // stage K-step ks into buffer buf: ALWAYS 3 loads per thread.
  auto STAGE = [&](int ks, int buf) {
    int d = ks >> 3;
    int dy = d / 3 - 1, dx = d - (d / 3) * 3 - 1;
    long shift = (long)(dy * 64 + dx) * 256 + (ks & 7) * 32;
    u16* base = &S[buf * 6144];
    ASYNC16(Ag + (long)ks * 32, base + wave * 512);
    const u16* s0 = ((unsigned)(yb0 + dy) < 64u && (unsigned)(xb + dx) < 64u)
                    ? Bg0 + shift : zp;
    const u16* s1 = ((unsigned)(yb1 + dy) < 64u && (unsigned)(xb + dx) < 64u)
                    ? Bg1 + shift : zp;
    ASYNC16(s0, base + 2048 + wave * 512);
    ASYNC16(s1, base + 4096 + wave * 512);
  };

  auto COMPUTE = [&](int buf) {
    const u16* as = &S[buf * 6144];
    const u16* bs = as + 2048;
    short8 af[2], bf[4];
#pragma unroll
    for (int s = 0; s < 2; s++) af[s] = *(const short8*)&as[(wi + s * 16 + li) * 32 + qx * 8];
#pragma unroll
    for (int s = 0; s < 4; s++) bf[s] = *(const short8*)&bs[(wj + s * 16 + li) * 32 + qx * 8];
#pragma unroll
    for (int si = 0; si < 2; si++)
#pragma unroll
      for (int sj = 0; sj < 4; sj++)
        acc[si][sj] = __builtin_amdgcn_mfma_f32_16x16x32_bf16(af[si], bf[sj], acc[si][sj], 0, 0, 0);
  };

  STAGE(0, 0); STAGE(1, 1); STAGE(2, 2);   // 9 loads in flight

  int cur = 0;
#pragma unroll 1
  for (int ks = 0; ks < 69; ks++) {
    asm volatile("s_waitcnt vmcnt(6)" ::: "memory");   // stage ks landed (mine)
    __builtin_amdgcn_s_barrier();                      // everyone's landed
    COMPUTE(cur);
    __builtin_amdgcn_s_barrier();                      // all reads of buf done
    STAGE(ks + 3, cur);                                // overwrite freed buffer
    cur = (cur == 2) ? 0 : cur + 1;
  }
  // ks = 69: stages 70,71 in flight (6)
  asm volatile("s_waitcnt vmcnt(6)" ::: "memory");
  __builtin_amdgcn_s_barrier();
  COMPUTE(cur);
  cur = (cur == 2) ? 0 : cur + 1;
  // ks = 70: stage 71 in flight (3)
  asm volatile("s_waitcnt vmcnt(3)" ::: "memory");
  __builtin_amdgcn_s_barrier();
  COMPUTE(cur);
  cur = (cur == 2) ? 0 : cur + 1;
  // ks = 71
  asm volatile("s_waitcnt vmcnt(0)" ::: "memory");
  __builtin_amdgcn_s_barrier();
  COMPUTE(cur);

#pragma unroll
  for (int si = 0; si < 2; si++)
#pragma unroll
    for (int sj = 0; sj < 4; sj++) {
      int col = n0 + wj + sj * 16 + li;              // n
      int row0 = i0 + wi + si * 16 + quad * 4;       // m base (multiple of 4)
      if (mode == 0) {
        f32x4 c4 = *(const f32x4*)&cb[(long)col * 256 + row0];
        us4v o;
#pragma unroll
        for (int r = 0; r < 4; r++) o[r] = f2b(acc[si][sj][r] + c4[r]);
        *(us4v*)&out16[(long)b * NB + (long)col * 256 + row0] = o;
      } else {
#pragma unroll
        for (int r = 0; r < 4; r++) {
          int row = row0 + r;
          float v = acc[si][sj][r] + cb[row];
          long a = (long)b * NB + (long)row * 4096 + col;
          float xv = xres[a];
          out32[a] = fmaf(v, xv, xv);
        }
      }
    }
}

// ---------------- host ----------------
extern "C" void kernel_launch(void* const* d_in, const int* in_sizes, int n_in,
                              void* d_out, int out_size, void* d_ws, size_t ws_size,
                              hipStream_t stream)
{
  const float* x   = (const float*)d_in[0];
  const float* qw  = (const float*)d_in[1];
  const float* qb  = (const float*)d_in[2];
  const float* kw  = (const float*)d_in[3];
  const float* kb  = (const float*)d_in[4];
  const float* vw  = (const float*)d_in[5];
  const float* vb  = (const float*)d_in[6];
  const float* rw  = (const float*)d_in[7];
  const float* rb  = (const float*)d_in[8];
  const float* c1w = (const float*)d_in[9];
  const float* c1b = (const float*)d_in[10];
  const float* c2w = (const float*)d_in[11];
  const float* c2b = (const float*)d_in[12];

  // ws layout (u16 units)
  u16* U     = (u16*)d_ws;
  u16* xT16  = U;                     // 8388608 ; later wvT16
  u16* Qt16  = U + 8388608;           // 8388608 ; later h1T16
  u16* KV16  = U + 16777216;          // 16777216 (K rows 0-255, V rows 256-511 per b)
  u16* wr2   = U + 33554432;          // 589824
  u16* kvT16 = U + 34144256;          // 524288
  float* Fws = (float*)(U + 34668544);
  float* ksum = Fws;                  // 2048
  float* vsum = Fws + 2048;           // 2048
  float* zbuf = Fws + 4096;           // 64 (zero page for conv OOB loads)

  // d_out scratch (all dead before conv2 writes d_out; conv2 reads NOTHING here)
  char* ob = (char*)d_out;
  float* kvpart = (float*)(ob + 0);           // 16777216 B
  float* den    = (float*)(ob + 16777216);    // 131072
  float* rsqK   = (float*)(ob + 16908288);    // 131072
  float* corr   = (float*)(ob + 17039360);    // 4194304  (layout [n][m])
  u16*   w1p16  = (u16*)(ob + 21233664);      // 1179648
  u16*   wr1    = (u16*)(ob + 22413312);      // 1179648
  float* T      = (float*)(ob + 23592960);    // 36864
  u16*   rwT16  = (u16*)(ob + 23629824);      // 131072
  u16*   qw16   = (u16*)(ob + 23760896);      // 131072
  u16*   kvw16  = (u16*)(ob + 23891968);      // 262144
  float* kvbias = (float*)(ob + 24154112);    // 2048
  float* outF   = (float*)d_out;

  u16* wvT16 = xT16;
  u16* h1T16 = Qt16;

  dim3 blk(256);

  prep1<<<5633, blk, 0, stream>>>(qw, kw, vw, rw, c1w, c2w, kb, vb,
                                  qw16, kvw16, rwT16, wr1, wr2, kvbias, zbuf);
  prep_T<<<9, blk, 0, stream>>>(c1w, rb, T);
  corr_k<<<4096, blk, 0, stream>>>(T, c1b, corr);
  transposeX<<<dim3(64, 4, 8), blk, 0, stream>>>(x, xT16);

  // w1' = wr1 @ rwT : folds rw into conv1 weights, layout [m][d*256+cv]
  gemm_nt<<<dim3(2, 18, 1), blk, 0, stream>>>(wr1, rwT16, w1p16,
      256, 256, 256, 0L, 0L, 0L, 256L, 1L, 0, nullptr, nullptr);
  // Qt[b][n][ck] = xT @ qw^T + qb
  gemm_nt<<<dim3(2, 32, 8), blk, 0, stream>>>(xT16, qw16, Qt16,
      256, 256, 256, NB, 0L, NB, 256L, 1L, 0, nullptr, qb);
  // KV[b][cq][n] = [kw|vw] @ x + [kb|vb]
  gemm_nt<<<dim3(32, 4, 8), blk, 0, stream>>>(kvw16, xT16, KV16,
      256, 256, 256, 0L, NB, 2 * NB, 4096L, 1L, 0, kvbias, nullptr);

  sumsqK<<<512, blk, 0, stream>>>(KV16, rsqK);
  scale_sums<<<4096, blk, 0, stream>>>(KV16, rsqK, ksum, vsum);
  normQden<<<8192, blk, 0, stream>>>(Qt16, ksum, den);

  gemm_kv<<<dim3(2, 2, 64), blk, 0, stream>>>(KV16, kvpart);
  reduce_kv<<<2048, blk, 0, stream>>>(kvpart, kvT16);

  // wvT[b][n][cv] = (Qt @ kv + vsum)*den   (coalesced stores)
  gemm_nt<<<dim3(2, 32, 8), blk, 0, stream>>>(Qt16, kvT16, wvT16,
      256, 256, 256, NB, 65536L, NB, 256L, 1L, 2, vsum, den);

  conv_gemm<<<1024, blk, 0, stream>>>(wvT16, w1p16, corr, nullptr, zbuf,
                                      h1T16, nullptr, 0);
  conv_gemm<<<1024, blk, 0, stream>>>(h1T16, wr2, c2b, x, zbuf,
                                      nullptr, outF, 1);
}

// Round 6
// 347.036 us; speedup vs baseline: 1.2082x; 1.1336x over previous
//
#include <hip/hip_runtime.h>
#include <math.h>

// HydraAttention R10 — conv_gemm re-tiled: full-M 256x128, BK=64, 512 threads,
// dbuf + counted vmcnt(6) (R9-proven skeleton); prep_T parallelized.
//
// R9 post-mortem: conv at 2427 cyc/step, work pipes ~900 -> ~1500/step is
// 2-phase scheduling overhead. R10 amortizes: steps 72->36 (BK=64), MFMA per
// wave-barrier 8->32, B-tile staged once for all M (L2 traffic per output
// halved). Sync structure identical to the R9 gemm_nt dbuf (STAGE(ks+1) ->
// vmcnt(6) -> barrier -> COMPUTE -> barrier), zero-page keeps per-wave vmcnt
// deterministic. 8-slot swizzle: stage qs8=(lane&7)^((lane>>3)&7), read slot
// ((kk*4+quad)^(lane&7)) — both-sides consistent (rule #21).
// prep_T: was 9 blocks (1 CU busy, 256 serial strided loads/thread) -> 256
// blocks, block-per-m, shuffle reduce.

typedef unsigned short u16;
typedef __attribute__((ext_vector_type(8))) short short8;
typedef __attribute__((ext_vector_type(4))) float f32x4;
typedef __attribute__((ext_vector_type(4))) unsigned short us4v;

#define ASYNC16(g, l) __builtin_amdgcn_global_load_lds( \
    (const __attribute__((address_space(1))) unsigned int*)(g), \
    (__attribute__((address_space(3))) unsigned int*)(l), 16, 0, 0)

static __device__ __forceinline__ float b2f(u16 h) {
  unsigned int u = ((unsigned int)h) << 16;
  return __builtin_bit_cast(float, u);
}
static __device__ __forceinline__ u16 f2b(float f) {
  unsigned int u = __builtin_bit_cast(unsigned int, f);
  u += 0x7fffu + ((u >> 16) & 1u);
  return (u16)(u >> 16);
}

#define NB 1048576L

// ---------------- prep1: weight converts/reorders + kvbias + zero page ----------------
__global__ __launch_bounds__(256) void prep1(
    const float* __restrict__ qw, const float* __restrict__ kw,
    const float* __restrict__ vw, const float* __restrict__ rw,
    const float* __restrict__ c1w, const float* __restrict__ c2w,
    const float* __restrict__ kb, const float* __restrict__ vb,
    u16* __restrict__ qw16, u16* __restrict__ kvw16, u16* __restrict__ rwT16,
    u16* __restrict__ wr1, u16* __restrict__ wr2,
    float* __restrict__ kvbias, float* __restrict__ zbuf)
{
  if (blockIdx.x == 5632) {
    int t = threadIdx.x;
    if (t < 256) { kvbias[t] = kb[t]; kvbias[t + 256] = vb[t]; }
    if (t < 64) zbuf[t] = 0.f;
    return;
  }
  long g = (long)blockIdx.x * 256 + threadIdx.x;
  if (g < 65536) {
    qw16[g] = f2b(qw[g]);
  } else if (g < 196608) {
    long e = g - 65536;
    kvw16[e] = f2b(e < 65536 ? kw[e] : vw[e - 65536]);
  } else if (g < 262144) {
    long e = g - 196608;
    int cv = e >> 8, co = e & 255;
    rwT16[e] = f2b(rw[co * 256 + cv]);
  } else if (g < 851968) {
    long e = g - 262144;
    int m = e / 2304, r = e - m * 2304;
    int d = r >> 8, c = r & 255;
    wr1[e] = f2b(c1w[m * 2304 + c * 9 + d]);
  } else {
    long e = g - 851968;
    int m = e / 2304, r = e - m * 2304;
    int d = r >> 8, c = r & 255;
    wr2[e] = f2b(c2w[m * 2304 + c * 9 + d]);
  }
}

// T[m*9+d] = sum_co c1w[m][co][d]*rb[co]  — block per m, shuffle reduce
__global__ __launch_bounds__(256) void prep_T(
    const float* __restrict__ c1w, const float* __restrict__ rb, float* __restrict__ T)
{
  int m = blockIdx.x, co = threadIdx.x;
  float r = rb[co];
  const float* p = c1w + (long)m * 2304 + co * 9;
  float lv[9];
#pragma unroll
  for (int d = 0; d < 9; d++) lv[d] = p[d] * r;
#pragma unroll
  for (int d = 0; d < 9; d++)
#pragma unroll
    for (int off = 32; off; off >>= 1) lv[d] += __shfl_down(lv[d], off, 64);
  __shared__ float red[4][9];
  int w = co >> 6, l = co & 63;
  if (l == 0)
#pragma unroll
    for (int d = 0; d < 9; d++) red[w][d] = lv[d];
  __syncthreads();
  if (co < 9) T[m * 9 + co] = red[0][co] + red[1][co] + red[2][co] + red[3][co];
}

// corr[p][m] = c1b[m] + sum_{t valid at p} T[m][t]   (TRANSPOSED layout [n][m])
__global__ __launch_bounds__(256) void corr_k(
    const float* __restrict__ T, const float* __restrict__ c1b, float* __restrict__ corr)
{
  int e = blockIdx.x * 256 + threadIdx.x;   // 1048576
  int m = e & 255, p = e >> 8;
  int y = p >> 6, xx = p & 63;
  float s = c1b[m];
#pragma unroll
  for (int d = 0; d < 9; d++) {
    int dy = d / 3 - 1, dx = d - (d / 3) * 3 - 1;
    if ((unsigned)(y + dy) < 64u && (unsigned)(xx + dx) < 64u) s += T[m * 9 + d];
  }
  corr[e] = s;                              // corr[p*256 + m], coalesced
}

// ---------------- x [b][c][n] f32 -> xT16 [b][n][c] bf16 ----------------
__global__ __launch_bounds__(256) void transposeX(
    const float* __restrict__ x, u16* __restrict__ xT)
{
  __shared__ float T[64][65];
  int n0 = blockIdx.x * 64, c0 = blockIdx.y * 64, b = blockIdx.z;
  int t = threadIdx.x;
#pragma unroll
  for (int i = 0; i < 4; i++) {
    int c = (t >> 4) + i * 16, nn = (t & 15) * 4;
    float4 v = *(const float4*)&x[(long)b * NB + (long)(c0 + c) * 4096 + n0 + nn];
    T[c][nn] = v.x; T[c][nn + 1] = v.y; T[c][nn + 2] = v.z; T[c][nn + 3] = v.w;
  }
  __syncthreads();
#pragma unroll
  for (int i = 0; i < 4; i++) {
    int n = (t >> 4) + i * 16, cc = (t & 15) * 4;
    us4v o;
#pragma unroll
    for (int e = 0; e < 4; e++) o[e] = f2b(T[cc + e][n]);
    *(us4v*)&xT[(long)b * NB + (long)(n0 + n) * 256 + c0 + cc] = o;
  }
}

// ---------------- generic NT bf16 MFMA GEMM: dbuf + counted vmcnt + T2 swizzle ----------------
// D[i][j] = sum_k A[i][k]*B[j][k]
// mode 0: v += (p1?p1[row]:0) + (p2?p2[col]:0)
// mode 2: v = (v + p1[b*256+col]) * p2[b*4096+row]
__global__ __launch_bounds__(256) void gemm_nt(
    const u16* __restrict__ A, const u16* __restrict__ B, u16* __restrict__ out,
    int K, int lda, int ldb, long sAb, long sBb, long sOb, long sR, long sC,
    int mode, const float* __restrict__ p1, const float* __restrict__ p2)
{
  __shared__ __align__(16) u16 As[2][128 * 32];
  __shared__ __align__(16) u16 Bs[2][128 * 32];
  int b = blockIdx.z;
  long i0 = (long)blockIdx.y * 128;
  long j0 = (long)blockIdx.x * 128;
  const u16* Ab = A + b * sAb + i0 * lda;
  const u16* Bb = B + b * sBb + j0 * ldb;
  int t = threadIdx.x, wave = t >> 6, lane = t & 63;
  int wi = (wave >> 1) * 64, wj = (wave & 1) * 64;
  int li = lane & 15, quad = lane >> 4;
  int qs = (lane & 3) ^ ((lane >> 3) & 3);   // swizzled source column (stage)
  int qx = quad ^ ((lane >> 1) & 3);         // swizzled quad-slot (read)
  int r0 = (wave * 128 + lane) >> 2;         // staging rows (h=0,1)
  int r1 = (wave * 128 + 64 + lane) >> 2;
  f32x4 acc[4][4];
#pragma unroll
  for (int i = 0; i < 4; i++)
#pragma unroll
    for (int j = 0; j < 4; j++) acc[i][j] = (f32x4){0.f, 0.f, 0.f, 0.f};

  // 4 ASYNC16 per thread per stage
  auto STAGE = [&](int kc, int buf) {
    int k0 = kc * 32;
    ASYNC16(Ab + (long)r0 * lda + k0 + qs * 8, &As[buf][(wave * 128) * 8]);
    ASYNC16(Bb + (long)r0 * ldb + k0 + qs * 8, &Bs[buf][(wave * 128) * 8]);
    ASYNC16(Ab + (long)r1 * lda + k0 + qs * 8, &As[buf][(wave * 128 + 64) * 8]);
    ASYNC16(Bb + (long)r1 * ldb + k0 + qs * 8, &Bs[buf][(wave * 128 + 64) * 8]);
  };

  int nk = K >> 5, cur = 0;
  STAGE(0, 0);
#pragma unroll 1
  for (int kc = 0; kc < nk; kc++) {
    if (kc + 1 < nk) {
      STAGE(kc + 1, cur ^ 1);
      asm volatile("s_waitcnt vmcnt(4)" ::: "memory");   // stage kc landed
    } else {
      asm volatile("s_waitcnt vmcnt(0)" ::: "memory");
    }
    __builtin_amdgcn_s_barrier();
    const u16* as = &As[cur][0];
    const u16* bs = &Bs[cur][0];
    short8 af[4], bf[4];
#pragma unroll
    for (int s = 0; s < 4; s++) af[s] = *(const short8*)&as[(wi + s * 16 + li) * 32 + qx * 8];
#pragma unroll
    for (int s = 0; s < 4; s++) bf[s] = *(const short8*)&bs[(wj + s * 16 + li) * 32 + qx * 8];
#pragma unroll
    for (int si = 0; si < 4; si++)
#pragma unroll
      for (int sj = 0; sj < 4; sj++)
        acc[si][sj] = __builtin_amdgcn_mfma_f32_16x16x32_bf16(af[si], bf[sj], acc[si][sj], 0, 0, 0);
    __builtin_amdgcn_s_barrier();                        // reads of cur done
    cur ^= 1;
  }

#pragma unroll
  for (int si = 0; si < 4; si++)
#pragma unroll
    for (int sj = 0; sj < 4; sj++) {
      long col = j0 + wj + sj * 16 + li;
#pragma unroll
      for (int r = 0; r < 4; r++) {
        long row = i0 + wi + si * 16 + quad * 4 + r;
        float v = acc[si][sj][r];
        if (mode == 0) {
          if (p1) v += p1[row];
          if (p2) v += p2[col];
        } else {
          v = (v + p1[b * 256 + col]) * p2[b * 4096 + row];
        }
        out[b * sOb + row * sR + col * sC] = f2b(v);
      }
    }
}

// ---------------- kv split-n GEMM: dbuf + counted vmcnt + T2 swizzle ----------------
__global__ __launch_bounds__(256) void gemm_kv(
    const u16* __restrict__ KV, float* __restrict__ part)
{
  __shared__ __align__(16) u16 As[2][128 * 32];
  __shared__ __align__(16) u16 Bs[2][128 * 32];
  int z = blockIdx.z;
  int b = z & 7, sp = z >> 3;
  long i0 = (long)blockIdx.y * 128;   // ck
  long j0 = (long)blockIdx.x * 128;   // cv
  const u16* Ab = KV + (long)b * 2 * NB + i0 * 4096;        // K rows
  const u16* Bb = KV + (long)b * 2 * NB + NB + j0 * 4096;   // V rows
  int t = threadIdx.x, wave = t >> 6, lane = t & 63;
  int wi = (wave >> 1) * 64, wj = (wave & 1) * 64;
  int li = lane & 15, quad = lane >> 4;
  int qs = (lane & 3) ^ ((lane >> 3) & 3);
  int qx = quad ^ ((lane >> 1) & 3);
  int r0 = (wave * 128 + lane) >> 2;
  int r1 = (wave * 128 + 64 + lane) >> 2;
  f32x4 acc[4][4];
#pragma unroll
  for (int i = 0; i < 4; i++)
#pragma unroll
    for (int j = 0; j < 4; j++) acc[i][j] = (f32x4){0.f, 0.f, 0.f, 0.f};

  auto STAGE = [&](int kc, int buf) {
    int k0 = sp * 512 + kc * 32;
    ASYNC16(Ab + (long)r0 * 4096 + k0 + qs * 8, &As[buf][(wave * 128) * 8]);
    ASYNC16(Bb + (long)r0 * 4096 + k0 + qs * 8, &Bs[buf][(wave * 128) * 8]);
    ASYNC16(Ab + (long)r1 * 4096 + k0 + qs * 8, &As[buf][(wave * 128 + 64) * 8]);
    ASYNC16(Bb + (long)r1 * 4096 + k0 + qs * 8, &Bs[buf][(wave * 128 + 64) * 8]);
  };

  int cur = 0;
  STAGE(0, 0);
#pragma unroll 1
  for (int kc = 0; kc < 16; kc++) {
    if (kc + 1 < 16) {
      STAGE(kc + 1, cur ^ 1);
      asm volatile("s_waitcnt vmcnt(4)" ::: "memory");
    } else {
      asm volatile("s_waitcnt vmcnt(0)" ::: "memory");
    }
    __builtin_amdgcn_s_barrier();
    const u16* as = &As[cur][0];
    const u16* bs = &Bs[cur][0];
    short8 af[4], bf[4];
#pragma unroll
    for (int s = 0; s < 4; s++) af[s] = *(const short8*)&as[(wi + s * 16 + li) * 32 + qx * 8];
#pragma unroll
    for (int s = 0; s < 4; s++) bf[s] = *(const short8*)&bs[(wj + s * 16 + li) * 32 + qx * 8];
#pragma unroll
    for (int si = 0; si < 4; si++)
#pragma unroll
      for (int sj = 0; sj < 4; sj++)
        acc[si][sj] = __builtin_amdgcn_mfma_f32_16x16x32_bf16(af[si], bf[sj], acc[si][sj], 0, 0, 0);
    __builtin_amdgcn_s_barrier();
    cur ^= 1;
  }

  float* outp = part + ((long)sp * 8 + b) * 65536;
#pragma unroll
  for (int si = 0; si < 4; si++)
#pragma unroll
    for (int sj = 0; sj < 4; sj++) {
      long col = j0 + wj + sj * 16 + li;   // cv
#pragma unroll
      for (int r = 0; r < 4; r++) {
        long row = i0 + wi + si * 16 + quad * 4 + r;  // ck
        outp[col * 256 + row] = acc[si][sj][r];
      }
    }
}

__global__ __launch_bounds__(256) void reduce_kv(
    const float* __restrict__ part, u16* __restrict__ kvT)
{
  int g = blockIdx.x * 256 + threadIdx.x;  // 524288
  float s = 0.f;
#pragma unroll
  for (int sp = 0; sp < 8; sp++) s += part[(long)sp * 524288 + g];
  kvT[g] = f2b(s);
}

// ---------------- fused: normalize Qt rows + den[b][n] = 1/(4096 + Qn.ksum + eps) ----------------
__global__ __launch_bounds__(256) void normQden(
    u16* __restrict__ Qt, const float* __restrict__ ksum, float* __restrict__ den)
{
  int row = blockIdx.x * 4 + (threadIdx.x >> 6);
  int lane = threadIdx.x & 63;
  int b = row >> 12;
  u16* p = Qt + (long)row * 256 + lane * 4;
  us4v v = *(const us4v*)p;
  float f0 = b2f(v[0]), f1 = b2f(v[1]), f2 = b2f(v[2]), f3 = b2f(v[3]);
  float s = f0 * f0 + f1 * f1 + f2 * f2 + f3 * f3;
#pragma unroll
  for (int m = 32; m; m >>= 1) s += __shfl_xor(s, m, 64);
  float r = 1.0f / sqrtf(s);
  float o0 = f0 * r, o1 = f1 * r, o2 = f2 * r, o3 = f3 * r;
  us4v o;
  o[0] = f2b(o0); o[1] = f2b(o1); o[2] = f2b(o2); o[3] = f2b(o3);
  *(us4v*)p = o;
  float4 ks = *(const float4*)&ksum[b * 256 + lane * 4];
  float s2 = o0 * ks.x + o1 * ks.y + o2 * ks.z + o3 * ks.w;
#pragma unroll
  for (int m = 32; m; m >>= 1) s2 += __shfl_xor(s2, m, 64);
  if (lane == 0) den[row] = 1.0f / (4096.0f + s2 + 1e-6f);
}

// ---------------- K column sumsq -> rsqK[b][n] (512 blocks = 2/CU) ----------------
__global__ __launch_bounds__(256) void sumsqK(
    const u16* __restrict__ KV, float* __restrict__ rsqK)
{
  __shared__ float red[16][68];
  int b = blockIdx.x >> 6, nc = blockIdx.x & 63;
  int n0 = nc * 64;
  int t = threadIdx.x;
  int nn = (t & 15) * 4, cg = t >> 4;
  const u16* base = KV + (long)b * 2 * NB;
  float s0 = 0.f, s1 = 0.f, s2 = 0.f, s3 = 0.f;
  for (int st = 0; st < 16; st++) {
    int c = cg + st * 16;
    us4v v = *(const us4v*)(base + (long)c * 4096 + n0 + nn);
    float a = b2f(v[0]), bb = b2f(v[1]), cc = b2f(v[2]), dd = b2f(v[3]);
    s0 = fmaf(a, a, s0); s1 = fmaf(bb, bb, s1);
    s2 = fmaf(cc, cc, s2); s3 = fmaf(dd, dd, s3);
  }
  red[cg][nn] = s0; red[cg][nn + 1] = s1; red[cg][nn + 2] = s2; red[cg][nn + 3] = s3;
  __syncthreads();
  if (t < 64) {
    float s = 0.f;
#pragma unroll
    for (int g = 0; g < 16; g++) s += red[g][t];
    rsqK[b * 4096 + n0 + t] = 1.0f / sqrtf(s);
  }
}

// ---------------- scale K rows by rsqK + ksum; V rows -> vsum ----------------
__global__ __launch_bounds__(256) void scale_sums(
    u16* __restrict__ KV, const float* __restrict__ rsqK,
    float* __restrict__ ksum, float* __restrict__ vsum)
{
  int z = blockIdx.x;
  int isV = z >> 11, rem = z & 2047, b = rem >> 8, c = rem & 255;
  u16* row = KV + (long)b * 2 * NB + (long)isV * NB + (long)c * 4096;
  const float* rq = rsqK + b * 4096;
  int t = threadIdx.x;
  float s = 0.f;
  short8 v0 = *(const short8*)&row[t * 16];
  short8 v1 = *(const short8*)&row[t * 16 + 8];
  if (!isV) {
    short8 o0, o1;
#pragma unroll
    for (int e = 0; e < 8; e++) {
      float a = b2f((u16)v0[e]) * rq[t * 16 + e];
      float bb = b2f((u16)v1[e]) * rq[t * 16 + 8 + e];
      s += a + bb;
      o0[e] = (short)f2b(a); o1[e] = (short)f2b(bb);
    }
    *(short8*)&row[t * 16] = o0;
    *(short8*)&row[t * 16 + 8] = o1;
  } else {
#pragma unroll
    for (int e = 0; e < 8; e++) s += b2f((u16)v0[e]) + b2f((u16)v1[e]);
  }
#pragma unroll
  for (int off = 32; off; off >>= 1) s += __shfl_down(s, off, 64);
  __shared__ float red[4];
  if ((t & 63) == 0) red[t >> 6] = s;
  __syncthreads();
  if (t == 0)
    (isV ? vsum : ksum)[b * 256 + c] = red[0] + red[1] + red[2] + red[3];
}

// ---------------- conv3x3 implicit GEMM: 256x128 tile, BK=64, dbuf counted vmcnt ----------------
// out[m][n] = sum_{d,c} W[m][d*256+c] * img[n + delta(d)][c], K = 2304 (36 BK=64 steps).
// One block = full M (256) x 128 n-positions (2 image rows). 512 threads,
// 8 waves of 64x64 output (WARPS_M=4, WARPS_N=2). Per buf: A 256x64 (32KB) +
// B 128x64 (16KB) = 48KB; 2 bufs = 96KB. Stage = 6 ASYNC16/thread (4 A + 2 B);
// OOB B granules read the zero page (count stays wave-uniform). Main loop:
// STAGE(ks+1) -> s_waitcnt vmcnt(6) -> s_barrier -> COMPUTE -> s_barrier.
// 8-slot swizzle: stage src slot qs8=(lane&7)^((lane>>3)&7); read slot
// ((kk*4+quad)^(lane&7)). Grid 256; b = lin&7 -> batch pinned to XCD.
// mode 0: out16[b][n][256] = acc + corrT[n][m]   (us4v store, f32x4 corr read)
// mode 1: out32[b][m][4096] = (acc + cb[m])*x + x
__global__ __launch_bounds__(512, 2) void conv_gemm(
    const u16* __restrict__ inT, const u16* __restrict__ wr,
    const float* __restrict__ cb, const float* __restrict__ xres,
    const float* __restrict__ zbuf,
    u16* __restrict__ out16, float* __restrict__ out32, int mode)
{
  __shared__ __align__(16) u16 S[2 * 24576];  // per buf: A @0 (16384 u16), B @16384 (8192 u16)

  int lin = blockIdx.x;            // 256 blocks
  int b   = lin & 7;               // XCD == batch under round-robin dispatch
  int n0  = (lin >> 3) * 128;      // n tile = 2 image rows; full M per block

  int t = threadIdx.x, wave = t >> 6, lane = t & 63;
  int wm = (wave >> 1) * 64, wn = (wave & 1) * 64;
  int li = lane & 15, quad = lane >> 4;
  int qs8 = (lane & 7) ^ ((lane >> 3) & 7);   // stage source slot (8-slot swizzle)
  const u16* inb = inT + (long)b * NB;

  // staging addresses: A rows i*64 + wave*8 + (lane>>3), i=0..3; B positions
  // pos_i = i*64 + wave*8 + (lane>>3), i=0..1 (y = yb0+i, x = wave*8+(lane>>3))
  int rr = wave * 8 + (lane >> 3);
  const u16* Ap0 = wr + (long)(rr)       * 2304 + qs8 * 8;
  const u16* Ap1 = wr + (long)(rr + 64)  * 2304 + qs8 * 8;
  const u16* Ap2 = wr + (long)(rr + 128) * 2304 + qs8 * 8;
  const u16* Ap3 = wr + (long)(rr + 192) * 2304 + qs8 * 8;
  const u16* Bp0 = inb + (long)(n0 + rr) * 256 + qs8 * 8;
  const u16* Bp1 = inb + (long)(n0 + 64 + rr) * 256 + qs8 * 8;
  const u16* zp  = (const u16*)zbuf + qs8 * 8;
  int yb0 = n0 >> 6, xb = rr;

  f32x4 acc[4][4];
#pragma unroll
  for (int i = 0; i < 4; i++)
#pragma unroll
    for (int j = 0; j < 4; j++) acc[i][j] = (f32x4){0.f, 0.f, 0.f, 0.f};

  // stage BK=64 step ks into buffer buf: ALWAYS 6 ASYNC16 per thread.
  auto STAGE = [&](int ks, int buf) {
    int d = ks >> 2;                          // tap (4 steps per tap)
    int dy = d / 3 - 1, dx = d - (d / 3) * 3 - 1;
    long shA = (long)ks * 64;                 // = d*256 + (ks&3)*64
    long shB = (long)(dy * 64 + dx) * 256 + (ks & 3) * 64;
    u16* base = &S[buf * 24576];
    ASYNC16(Ap0 + shA, base + wave * 512);
    ASYNC16(Ap1 + shA, base + 4096 + wave * 512);
    ASYNC16(Ap2 + shA, base + 8192 + wave * 512);
    ASYNC16(Ap3 + shA, base + 12288 + wave * 512);
    bool v0 = ((unsigned)(yb0 + dy) < 64u) && ((unsigned)(xb + dx) < 64u);
    bool v1 = ((unsigned)(yb0 + 1 + dy) < 64u) && ((unsigned)(xb + dx) < 64u);
    ASYNC16(v0 ? Bp0 + shB : zp, base + 16384 + wave * 512);
    ASYNC16(v1 ? Bp1 + shB : zp, base + 20480 + wave * 512);
  };

  int cur = 0;
  STAGE(0, 0);
#pragma unroll 1
  for (int ks = 0; ks < 36; ks++) {
    if (ks + 1 < 36) {
      STAGE(ks + 1, cur ^ 1);
      asm volatile("s_waitcnt vmcnt(6)" ::: "memory");   // stage ks landed
    } else {
      asm volatile("s_waitcnt vmcnt(0)" ::: "memory");
    }
    __builtin_amdgcn_s_barrier();
    const u16* as = &S[cur * 24576];
    const u16* bs = as + 16384;
#pragma unroll
    for (int kk = 0; kk < 2; kk++) {
      short8 af[4], bf[4];
      int slot = (((kk << 2) | quad) ^ (lane & 7)) * 8;
#pragma unroll
      for (int s = 0; s < 4; s++) af[s] = *(const short8*)&as[(wm + s * 16 + li) * 64 + slot];
#pragma unroll
      for (int s = 0; s < 4; s++) bf[s] = *(const short8*)&bs[(wn + s * 16 + li) * 64 + slot];
#pragma unroll
      for (int si = 0; si < 4; si++)
#pragma unroll
        for (int sj = 0; sj < 4; sj++)
          acc[si][sj] = __builtin_amdgcn_mfma_f32_16x16x32_bf16(af[si], bf[sj], acc[si][sj], 0, 0, 0);
    }
    __builtin_amdgcn_s_barrier();                        // all reads of cur done
    cur ^= 1;
  }

#pragma unroll
  for (int si = 0; si < 4; si++)
#pragma unroll
    for (int sj = 0; sj < 4; sj++) {
      int n = n0 + wn + sj * 16 + li;                // n
      int m0 = wm + si * 16 + quad * 4;              // m base (multiple of 4)
      if (mode == 0) {
        f32x4 c4 = *(const f32x4*)&cb[(long)n * 256 + m0];
        us4v o;
#pragma unroll
        for (int r = 0; r < 4; r++) o[r] = f2b(acc[si][sj][r] + c4[r]);
        *(us4v*)&out16[(long)b * NB + (long)n * 256 + m0] = o;
      } else {
#pragma unroll
        for (int r = 0; r < 4; r++) {
          int m = m0 + r;
          float v = acc[si][sj][r] + cb[m];
          long a = (long)b * NB + (long)m * 4096 + n;
          float xv = xres[a];
          out32[a] = fmaf(v, xv, xv);
        }
      }
    }
}

// ---------------- host ----------------
extern "C" void kernel_launch(void* const* d_in, const int* in_sizes, int n_in,
                              void* d_out, int out_size, void* d_ws, size_t ws_size,
                              hipStream_t stream)
{
  const float* x   = (const float*)d_in[0];
  const float* qw  = (const float*)d_in[1];
  const float* qb  = (const float*)d_in[2];
  const float* kw  = (const float*)d_in[3];
  const float* kb  = (const float*)d_in[4];
  const float* vw  = (const float*)d_in[5];
  const float* vb  = (const float*)d_in[6];
  const float* rw  = (const float*)d_in[7];
  const float* rb  = (const float*)d_in[8];
  const float* c1w = (const float*)d_in[9];
  const float* c1b = (const float*)d_in[10];
  const float* c2w = (const float*)d_in[11];
  const float* c2b = (const float*)d_in[12];

  // ws layout (u16 units)
  u16* U     = (u16*)d_ws;
  u16* xT16  = U;                     // 8388608 ; later wvT16
  u16* Qt16  = U + 8388608;           // 8388608 ; later h1T16
  u16* KV16  = U + 16777216;          // 16777216 (K rows 0-255, V rows 256-511 per b)
  u16* wr2   = U + 33554432;          // 589824
  u16* kvT16 = U + 34144256;          // 524288
  float* Fws = (float*)(U + 34668544);
  float* ksum = Fws;                  // 2048
  float* vsum = Fws + 2048;           // 2048
  float* zbuf = Fws + 4096;           // 64 (zero page for conv OOB loads)

  // d_out scratch (all dead before conv2 writes d_out; conv2 reads NOTHING here)
  char* ob = (char*)d_out;
  float* kvpart = (float*)(ob + 0);           // 16777216 B
  float* den    = (float*)(ob + 16777216);    // 131072
  float* rsqK   = (float*)(ob + 16908288);    // 131072
  float* corr   = (float*)(ob + 17039360);    // 4194304  (layout [n][m])
  u16*   w1p16  = (u16*)(ob + 21233664);      // 1179648
  u16*   wr1    = (u16*)(ob + 22413312);      // 1179648
  float* T      = (float*)(ob + 23592960);    // 36864
  u16*   rwT16  = (u16*)(ob + 23629824);      // 131072
  u16*   qw16   = (u16*)(ob + 23760896);      // 131072
  u16*   kvw16  = (u16*)(ob + 23891968);      // 262144
  float* kvbias = (float*)(ob + 24154112);    // 2048
  float* outF   = (float*)d_out;

  u16* wvT16 = xT16;
  u16* h1T16 = Qt16;

  dim3 blk(256);

  prep1<<<5633, blk, 0, stream>>>(qw, kw, vw, rw, c1w, c2w, kb, vb,
                                  qw16, kvw16, rwT16, wr1, wr2, kvbias, zbuf);
  prep_T<<<256, blk, 0, stream>>>(c1w, rb, T);
  corr_k<<<4096, blk, 0, stream>>>(T, c1b, corr);
  transposeX<<<dim3(64, 4, 8), blk, 0, stream>>>(x, xT16);

  // w1' = wr1 @ rwT : folds rw into conv1 weights, layout [m][d*256+cv]
  gemm_nt<<<dim3(2, 18, 1), blk, 0, stream>>>(wr1, rwT16, w1p16,
      256, 256, 256, 0L, 0L, 0L, 256L, 1L, 0, nullptr, nullptr);
  // Qt[b][n][ck] = xT @ qw^T + qb
  gemm_nt<<<dim3(2, 32, 8), blk, 0, stream>>>(xT16, qw16, Qt16,
      256, 256, 256, NB, 0L, NB, 256L, 1L, 0, nullptr, qb);
  // KV[b][cq][n] = [kw|vw] @ x + [kb|vb]
  gemm_nt<<<dim3(32, 4, 8), blk, 0, stream>>>(kvw16, xT16, KV16,
      256, 256, 256, 0L, NB, 2 * NB, 4096L, 1L, 0, kvbias, nullptr);

  sumsqK<<<512, blk, 0, stream>>>(KV16, rsqK);
  scale_sums<<<4096, blk, 0, stream>>>(KV16, rsqK, ksum, vsum);
  normQden<<<8192, blk, 0, stream>>>(Qt16, ksum, den);

  gemm_kv<<<dim3(2, 2, 64), blk, 0, stream>>>(KV16, kvpart);
  reduce_kv<<<2048, blk, 0, stream>>>(kvpart, kvT16);

  // wvT[b][n][cv] = (Qt @ kv + vsum)*den   (coalesced stores)
  gemm_nt<<<dim3(2, 32, 8), blk, 0, stream>>>(Qt16, kvT16, wvT16,
      256, 256, 256, NB, 65536L, NB, 256L, 1L, 2, vsum, den);

  conv_gemm<<<256, 512, 0, stream>>>(wvT16, w1p16, corr, nullptr, zbuf,
                                     h1T16, nullptr, 0);
  conv_gemm<<<256, 512, 0, stream>>>(h1T16, wr2, c2b, x, zbuf,
                                     nullptr, outF, 1);
}

// Round 7
// 339.890 us; speedup vs baseline: 1.2336x; 1.0210x over previous
//
#include <hip/hip_runtime.h>
#include <math.h>

// HydraAttention R11 — mid-tier consolidation. Convs (2x53.8us, R10 structure)
// untouched; the other 239us across 13 launches is now the majority.
//   1. gemm_nt + gemm_kv -> BK=64 with the R10-proven skeleton (8 ASYNC16 per
//      thread per stage, counted vmcnt(8), 128B-row-stride LDS + 8-slot swizzle
//      that measured ZERO bank conflicts in R10). Step counts halve.
//   2. normQden -> read-only qden (rq=1/||Q||, den) — saves the 16MB Qt
//      rewrite; wv epilogue becomes (acc*rq + vsum)*den  (mode2 + p3).
//   3. prep_T folded into prep1; corr_k + transposeX fused. 15 -> 13 launches.

typedef unsigned short u16;
typedef __attribute__((ext_vector_type(8))) short short8;
typedef __attribute__((ext_vector_type(4))) float f32x4;
typedef __attribute__((ext_vector_type(4))) unsigned short us4v;

#define ASYNC16(g, l) __builtin_amdgcn_global_load_lds( \
    (const __attribute__((address_space(1))) unsigned int*)(g), \
    (__attribute__((address_space(3))) unsigned int*)(l), 16, 0, 0)

static __device__ __forceinline__ float b2f(u16 h) {
  unsigned int u = ((unsigned int)h) << 16;
  return __builtin_bit_cast(float, u);
}
static __device__ __forceinline__ u16 f2b(float f) {
  unsigned int u = __builtin_bit_cast(unsigned int, f);
  u += 0x7fffu + ((u >> 16) & 1u);
  return (u16)(u >> 16);
}

#define NB 1048576L

// ---------------- prep1: weight converts/reorders + kvbias + zero page + prep_T ----------------
__global__ __launch_bounds__(256) void prep1(
    const float* __restrict__ qw, const float* __restrict__ kw,
    const float* __restrict__ vw, const float* __restrict__ rw,
    const float* __restrict__ c1w, const float* __restrict__ c2w,
    const float* __restrict__ kb, const float* __restrict__ vb,
    const float* __restrict__ rb,
    u16* __restrict__ qw16, u16* __restrict__ kvw16, u16* __restrict__ rwT16,
    u16* __restrict__ wr1, u16* __restrict__ wr2,
    float* __restrict__ kvbias, float* __restrict__ zbuf, float* __restrict__ T)
{
  if (blockIdx.x >= 5633) {
    // prep_T: T[m*9+d] = sum_co c1w[m][co][d]*rb[co]
    int m = blockIdx.x - 5633, co = threadIdx.x;
    float r = rb[co];
    const float* p = c1w + (long)m * 2304 + co * 9;
    float lv[9];
#pragma unroll
    for (int d = 0; d < 9; d++) lv[d] = p[d] * r;
#pragma unroll
    for (int d = 0; d < 9; d++)
#pragma unroll
      for (int off = 32; off; off >>= 1) lv[d] += __shfl_down(lv[d], off, 64);
    __shared__ float red[4][9];
    int w = co >> 6, l = co & 63;
    if (l == 0)
#pragma unroll
      for (int d = 0; d < 9; d++) red[w][d] = lv[d];
    __syncthreads();
    if (co < 9) T[m * 9 + co] = red[0][co] + red[1][co] + red[2][co] + red[3][co];
    return;
  }
  if (blockIdx.x == 5632) {
    int t = threadIdx.x;
    if (t < 256) { kvbias[t] = kb[t]; kvbias[t + 256] = vb[t]; }
    if (t < 64) zbuf[t] = 0.f;
    return;
  }
  long g = (long)blockIdx.x * 256 + threadIdx.x;
  if (g < 65536) {
    qw16[g] = f2b(qw[g]);
  } else if (g < 196608) {
    long e = g - 65536;
    kvw16[e] = f2b(e < 65536 ? kw[e] : vw[e - 65536]);
  } else if (g < 262144) {
    long e = g - 196608;
    int cv = e >> 8, co = e & 255;
    rwT16[e] = f2b(rw[co * 256 + cv]);
  } else if (g < 851968) {
    long e = g - 262144;
    int m = e / 2304, r = e - m * 2304;
    int d = r >> 8, c = r & 255;
    wr1[e] = f2b(c1w[m * 2304 + c * 9 + d]);
  } else {
    long e = g - 851968;
    int m = e / 2304, r = e - m * 2304;
    int d = r >> 8, c = r & 255;
    wr2[e] = f2b(c2w[m * 2304 + c * 9 + d]);
  }
}

// ---------------- fused: corr field + x transpose ----------------
// blocks 0..4095:   corr[p][m] = c1b[m] + sum_{t valid at p} T[m][t]  ([n][m] layout)
// blocks 4096..6143: x [b][c][n] f32 -> xT16 [b][n][c] bf16
__global__ __launch_bounds__(256) void corr_transX(
    const float* __restrict__ T, const float* __restrict__ c1b,
    float* __restrict__ corr,
    const float* __restrict__ x, u16* __restrict__ xT)
{
  __shared__ float Tl[64][65];
  int bb = blockIdx.x, t = threadIdx.x;
  if (bb < 4096) {
    int e = bb * 256 + t;
    int m = e & 255, p = e >> 8;
    int y = p >> 6, xx = p & 63;
    float s = c1b[m];
#pragma unroll
    for (int d = 0; d < 9; d++) {
      int dy = d / 3 - 1, dx = d - (d / 3) * 3 - 1;
      if ((unsigned)(y + dy) < 64u && (unsigned)(xx + dx) < 64u) s += T[m * 9 + d];
    }
    corr[e] = s;
    return;
  }
  int lin = bb - 4096;
  int n0 = (lin & 63) * 64, c0 = ((lin >> 6) & 3) * 64, b = lin >> 8;
#pragma unroll
  for (int i = 0; i < 4; i++) {
    int c = (t >> 4) + i * 16, nn = (t & 15) * 4;
    float4 v = *(const float4*)&x[(long)b * NB + (long)(c0 + c) * 4096 + n0 + nn];
    Tl[c][nn] = v.x; Tl[c][nn + 1] = v.y; Tl[c][nn + 2] = v.z; Tl[c][nn + 3] = v.w;
  }
  __syncthreads();
#pragma unroll
  for (int i = 0; i < 4; i++) {
    int n = (t >> 4) + i * 16, cc = (t & 15) * 4;
    us4v o;
#pragma unroll
    for (int e = 0; e < 4; e++) o[e] = f2b(Tl[cc + e][n]);
    *(us4v*)&xT[(long)b * NB + (long)(n0 + n) * 256 + c0 + cc] = o;
  }
}

// ---------------- generic NT bf16 MFMA GEMM: BK=64, dbuf + counted vmcnt(8) ----------------
// D[i][j] = sum_k A[i][k]*B[j][k]
// mode 0: v += (p1?p1[row]:0) + (p2?p2[col]:0)
// mode 2: v = (v*p3[b*4096+row] + p1[b*256+col]) * p2[b*4096+row]
__global__ __launch_bounds__(256) void gemm_nt(
    const u16* __restrict__ A, const u16* __restrict__ B, u16* __restrict__ out,
    int K, int lda, int ldb, long sAb, long sBb, long sOb, long sR, long sC,
    int mode, const float* __restrict__ p1, const float* __restrict__ p2,
    const float* __restrict__ p3)
{
  __shared__ __align__(16) u16 As[2][128 * 64];   // 16KB per buf
  __shared__ __align__(16) u16 Bs[2][128 * 64];   // total 64KB
  int b = blockIdx.z;
  long i0 = (long)blockIdx.y * 128;
  long j0 = (long)blockIdx.x * 128;
  const u16* Ab = A + b * sAb + i0 * lda;
  const u16* Bb = B + b * sBb + j0 * ldb;
  int t = threadIdx.x, wave = t >> 6, lane = t & 63;
  int wi = (wave >> 1) * 64, wj = (wave & 1) * 64;
  int li = lane & 15, quad = lane >> 4;
  int qs8 = (lane & 7) ^ ((lane >> 3) & 7);    // stage source slot (R10 swizzle)
  f32x4 acc[4][4];
#pragma unroll
  for (int i = 0; i < 4; i++)
#pragma unroll
    for (int j = 0; j < 4; j++) acc[i][j] = (f32x4){0.f, 0.f, 0.f, 0.f};

  // 8 ASYNC16 per thread per stage (4 A-issues + 4 B-issues)
  auto STAGE = [&](int kc, int buf) {
    long k0 = (long)kc * 64 + qs8 * 8;
#pragma unroll
    for (int j = 0; j < 4; j++) {
      int row = (wave * 4 + j) * 8 + (lane >> 3);
      ASYNC16(Ab + (long)row * lda + k0, &As[buf][(wave * 4 + j) * 512]);
      ASYNC16(Bb + (long)row * ldb + k0, &Bs[buf][(wave * 4 + j) * 512]);
    }
  };

  int nk = K >> 6, cur = 0;
  STAGE(0, 0);
#pragma unroll 1
  for (int kc = 0; kc < nk; kc++) {
    if (kc + 1 < nk) {
      STAGE(kc + 1, cur ^ 1);
      asm volatile("s_waitcnt vmcnt(8)" ::: "memory");   // stage kc landed
    } else {
      asm volatile("s_waitcnt vmcnt(0)" ::: "memory");
    }
    __builtin_amdgcn_s_barrier();
    const u16* as = &As[cur][0];
    const u16* bs = &Bs[cur][0];
#pragma unroll
    for (int kk = 0; kk < 2; kk++) {
      short8 af[4], bf[4];
      int slot = (((kk << 2) | quad) ^ (li & 7)) * 8;
#pragma unroll
      for (int s = 0; s < 4; s++) af[s] = *(const short8*)&as[(wi + s * 16 + li) * 64 + slot];
#pragma unroll
      for (int s = 0; s < 4; s++) bf[s] = *(const short8*)&bs[(wj + s * 16 + li) * 64 + slot];
#pragma unroll
      for (int si = 0; si < 4; si++)
#pragma unroll
        for (int sj = 0; sj < 4; sj++)
          acc[si][sj] = __builtin_amdgcn_mfma_f32_16x16x32_bf16(af[si], bf[sj], acc[si][sj], 0, 0, 0);
    }
    __builtin_amdgcn_s_barrier();                        // reads of cur done
    cur ^= 1;
  }

#pragma unroll
  for (int si = 0; si < 4; si++)
#pragma unroll
    for (int sj = 0; sj < 4; sj++) {
      long col = j0 + wj + sj * 16 + li;
#pragma unroll
      for (int r = 0; r < 4; r++) {
        long row = i0 + wi + si * 16 + quad * 4 + r;
        float v = acc[si][sj][r];
        if (mode == 0) {
          if (p1) v += p1[row];
          if (p2) v += p2[col];
        } else {
          v = (v * p3[b * 4096 + row] + p1[b * 256 + col]) * p2[b * 4096 + row];
        }
        out[b * sOb + row * sR + col * sC] = f2b(v);
      }
    }
}

// ---------------- kv split-n GEMM: BK=64, dbuf + counted vmcnt(8) ----------------
__global__ __launch_bounds__(256) void gemm_kv(
    const u16* __restrict__ KV, float* __restrict__ part)
{
  __shared__ __align__(16) u16 As[2][128 * 64];
  __shared__ __align__(16) u16 Bs[2][128 * 64];
  int z = blockIdx.z;
  int b = z & 7, sp = z >> 3;
  long i0 = (long)blockIdx.y * 128;   // ck
  long j0 = (long)blockIdx.x * 128;   // cv
  const u16* Ab = KV + (long)b * 2 * NB + i0 * 4096;        // K rows
  const u16* Bb = KV + (long)b * 2 * NB + NB + j0 * 4096;   // V rows
  int t = threadIdx.x, wave = t >> 6, lane = t & 63;
  int wi = (wave >> 1) * 64, wj = (wave & 1) * 64;
  int li = lane & 15, quad = lane >> 4;
  int qs8 = (lane & 7) ^ ((lane >> 3) & 7);
  f32x4 acc[4][4];
#pragma unroll
  for (int i = 0; i < 4; i++)
#pragma unroll
    for (int j = 0; j < 4; j++) acc[i][j] = (f32x4){0.f, 0.f, 0.f, 0.f};

  auto STAGE = [&](int kc, int buf) {
    long k0 = (long)sp * 512 + kc * 64 + qs8 * 8;
#pragma unroll
    for (int j = 0; j < 4; j++) {
      int row = (wave * 4 + j) * 8 + (lane >> 3);
      ASYNC16(Ab + (long)row * 4096 + k0, &As[buf][(wave * 4 + j) * 512]);
      ASYNC16(Bb + (long)row * 4096 + k0, &Bs[buf][(wave * 4 + j) * 512]);
    }
  };

  int cur = 0;
  STAGE(0, 0);
#pragma unroll 1
  for (int kc = 0; kc < 8; kc++) {
    if (kc + 1 < 8) {
      STAGE(kc + 1, cur ^ 1);
      asm volatile("s_waitcnt vmcnt(8)" ::: "memory");
    } else {
      asm volatile("s_waitcnt vmcnt(0)" ::: "memory");
    }
    __builtin_amdgcn_s_barrier();
    const u16* as = &As[cur][0];
    const u16* bs = &Bs[cur][0];
#pragma unroll
    for (int kk = 0; kk < 2; kk++) {
      short8 af[4], bf[4];
      int slot = (((kk << 2) | quad) ^ (li & 7)) * 8;
#pragma unroll
      for (int s = 0; s < 4; s++) af[s] = *(const short8*)&as[(wi + s * 16 + li) * 64 + slot];
#pragma unroll
      for (int s = 0; s < 4; s++) bf[s] = *(const short8*)&bs[(wj + s * 16 + li) * 64 + slot];
#pragma unroll
      for (int si = 0; si < 4; si++)
#pragma unroll
        for (int sj = 0; sj < 4; sj++)
          acc[si][sj] = __builtin_amdgcn_mfma_f32_16x16x32_bf16(af[si], bf[sj], acc[si][sj], 0, 0, 0);
    }
    __builtin_amdgcn_s_barrier();
    cur ^= 1;
  }

  float* outp = part + ((long)sp * 8 + b) * 65536;
#pragma unroll
  for (int si = 0; si < 4; si++)
#pragma unroll
    for (int sj = 0; sj < 4; sj++) {
      long col = j0 + wj + sj * 16 + li;   // cv
#pragma unroll
      for (int r = 0; r < 4; r++) {
        long row = i0 + wi + si * 16 + quad * 4 + r;  // ck
        outp[col * 256 + row] = acc[si][sj][r];
      }
    }
}

__global__ __launch_bounds__(256) void reduce_kv(
    const float* __restrict__ part, u16* __restrict__ kvT)
{
  int g = blockIdx.x * 256 + threadIdx.x;  // 524288
  float s = 0.f;
#pragma unroll
  for (int sp = 0; sp < 8; sp++) s += part[(long)sp * 524288 + g];
  kvT[g] = f2b(s);
}

// ---------------- qden: read-only over Qt -> rq[row]=1/||Q||, den[row] ----------------
__global__ __launch_bounds__(256) void qden(
    const u16* __restrict__ Qt, const float* __restrict__ ksum,
    float* __restrict__ rq, float* __restrict__ den)
{
  int row = blockIdx.x * 4 + (threadIdx.x >> 6);
  int lane = threadIdx.x & 63;
  int b = row >> 12;
  us4v v = *(const us4v*)(Qt + (long)row * 256 + lane * 4);
  float4 ks = *(const float4*)&ksum[b * 256 + lane * 4];
  float f0 = b2f(v[0]), f1 = b2f(v[1]), f2 = b2f(v[2]), f3 = b2f(v[3]);
  float s = f0 * f0 + f1 * f1 + f2 * f2 + f3 * f3;
  float s2 = f0 * ks.x + f1 * ks.y + f2 * ks.z + f3 * ks.w;
#pragma unroll
  for (int m = 32; m; m >>= 1) {
    s += __shfl_xor(s, m, 64);
    s2 += __shfl_xor(s2, m, 64);
  }
  if (lane == 0) {
    float r = 1.0f / sqrtf(s);
    rq[row] = r;
    den[row] = 1.0f / (4096.0f + s2 * r + 1e-6f);
  }
}

// ---------------- K column sumsq -> rsqK[b][n] (512 blocks = 2/CU) ----------------
__global__ __launch_bounds__(256) void sumsqK(
    const u16* __restrict__ KV, float* __restrict__ rsqK)
{
  __shared__ float red[16][68];
  int b = blockIdx.x >> 6, nc = blockIdx.x & 63;
  int n0 = nc * 64;
  int t = threadIdx.x;
  int nn = (t & 15) * 4, cg = t >> 4;
  const u16* base = KV + (long)b * 2 * NB;
  float s0 = 0.f, s1 = 0.f, s2 = 0.f, s3 = 0.f;
  for (int st = 0; st < 16; st++) {
    int c = cg + st * 16;
    us4v v = *(const us4v*)(base + (long)c * 4096 + n0 + nn);
    float a = b2f(v[0]), bb = b2f(v[1]), cc = b2f(v[2]), dd = b2f(v[3]);
    s0 = fmaf(a, a, s0); s1 = fmaf(bb, bb, s1);
    s2 = fmaf(cc, cc, s2); s3 = fmaf(dd, dd, s3);
  }
  red[cg][nn] = s0; red[cg][nn + 1] = s1; red[cg][nn + 2] = s2; red[cg][nn + 3] = s3;
  __syncthreads();
  if (t < 64) {
    float s = 0.f;
#pragma unroll
    for (int g = 0; g < 16; g++) s += red[g][t];
    rsqK[b * 4096 + n0 + t] = 1.0f / sqrtf(s);
  }
}

// ---------------- scale K rows by rsqK + ksum; V rows -> vsum ----------------
__global__ __launch_bounds__(256) void scale_sums(
    u16* __restrict__ KV, const float* __restrict__ rsqK,
    float* __restrict__ ksum, float* __restrict__ vsum)
{
  int z = blockIdx.x;
  int isV = z >> 11, rem = z & 2047, b = rem >> 8, c = rem & 255;
  u16* row = KV + (long)b * 2 * NB + (long)isV * NB + (long)c * 4096;
  const float* rq = rsqK + b * 4096;
  int t = threadIdx.x;
  float s = 0.f;
  short8 v0 = *(const short8*)&row[t * 16];
  short8 v1 = *(const short8*)&row[t * 16 + 8];
  if (!isV) {
    short8 o0, o1;
#pragma unroll
    for (int e = 0; e < 8; e++) {
      float a = b2f((u16)v0[e]) * rq[t * 16 + e];
      float bb = b2f((u16)v1[e]) * rq[t * 16 + 8 + e];
      s += a + bb;
      o0[e] = (short)f2b(a); o1[e] = (short)f2b(bb);
    }
    *(short8*)&row[t * 16] = o0;
    *(short8*)&row[t * 16 + 8] = o1;
  } else {
#pragma unroll
    for (int e = 0; e < 8; e++) s += b2f((u16)v0[e]) + b2f((u16)v1[e]);
  }
#pragma unroll
  for (int off = 32; off; off >>= 1) s += __shfl_down(s, off, 64);
  __shared__ float red[4];
  if ((t & 63) == 0) red[t >> 6] = s;
  __syncthreads();
  if (t == 0)
    (isV ? vsum : ksum)[b * 256 + c] = red[0] + red[1] + red[2] + red[3];
}

// ---------------- conv3x3 implicit GEMM: 256x128 tile, BK=64 (unchanged from R10) ----------------
__global__ __launch_bounds__(512, 2) void conv_gemm(
    const u16* __restrict__ inT, const u16* __restrict__ wr,
    const float* __restrict__ cb, const float* __restrict__ xres,
    const float* __restrict__ zbuf,
    u16* __restrict__ out16, float* __restrict__ out32, int mode)
{
  __shared__ __align__(16) u16 S[2 * 24576];  // per buf: A @0 (16384 u16), B @16384 (8192 u16)

  int lin = blockIdx.x;            // 256 blocks
  int b   = lin & 7;               // XCD == batch under round-robin dispatch
  int n0  = (lin >> 3) * 128;      // n tile = 2 image rows; full M per block

  int t = threadIdx.x, wave = t >> 6, lane = t & 63;
  int wm = (wave >> 1) * 64, wn = (wave & 1) * 64;
  int li = lane & 15, quad = lane >> 4;
  int qs8 = (lane & 7) ^ ((lane >> 3) & 7);   // stage source slot (8-slot swizzle)
  const u16* inb = inT + (long)b * NB;

  int rr = wave * 8 + (lane >> 3);
  const u16* Ap0 = wr + (long)(rr)       * 2304 + qs8 * 8;
  const u16* Ap1 = wr + (long)(rr + 64)  * 2304 + qs8 * 8;
  const u16* Ap2 = wr + (long)(rr + 128) * 2304 + qs8 * 8;
  const u16* Ap3 = wr + (long)(rr + 192) * 2304 + qs8 * 8;
  const u16* Bp0 = inb + (long)(n0 + rr) * 256 + qs8 * 8;
  const u16* Bp1 = inb + (long)(n0 + 64 + rr) * 256 + qs8 * 8;
  const u16* zp  = (const u16*)zbuf + qs8 * 8;
  int yb0 = n0 >> 6, xb = rr;

  f32x4 acc[4][4];
#pragma unroll
  for (int i = 0; i < 4; i++)
#pragma unroll
    for (int j = 0; j < 4; j++) acc[i][j] = (f32x4){0.f, 0.f, 0.f, 0.f};

  auto STAGE = [&](int ks, int buf) {
    int d = ks >> 2;                          // tap (4 steps per tap)
    int dy = d / 3 - 1, dx = d - (d / 3) * 3 - 1;
    long shA = (long)ks * 64;                 // = d*256 + (ks&3)*64
    long shB = (long)(dy * 64 + dx) * 256 + (ks & 3) * 64;
    u16* base = &S[buf * 24576];
    ASYNC16(Ap0 + shA, base + wave * 512);
    ASYNC16(Ap1 + shA, base + 4096 + wave * 512);
    ASYNC16(Ap2 + shA, base + 8192 + wave * 512);
    ASYNC16(Ap3 + shA, base + 12288 + wave * 512);
    bool v0 = ((unsigned)(yb0 + dy) < 64u) && ((unsigned)(xb + dx) < 64u);
    bool v1 = ((unsigned)(yb0 + 1 + dy) < 64u) && ((unsigned)(xb + dx) < 64u);
    ASYNC16(v0 ? Bp0 + shB : zp, base + 16384 + wave * 512);
    ASYNC16(v1 ? Bp1 + shB : zp, base + 20480 + wave * 512);
  };

  int cur = 0;
  STAGE(0, 0);
#pragma unroll 1
  for (int ks = 0; ks < 36; ks++) {
    if (ks + 1 < 36) {
      STAGE(ks + 1, cur ^ 1);
      asm volatile("s_waitcnt vmcnt(6)" ::: "memory");   // stage ks landed
    } else {
      asm volatile("s_waitcnt vmcnt(0)" ::: "memory");
    }
    __builtin_amdgcn_s_barrier();
    const u16* as = &S[cur * 24576];
    const u16* bs = as + 16384;
#pragma unroll
    for (int kk = 0; kk < 2; kk++) {
      short8 af[4], bf[4];
      int slot = (((kk << 2) | quad) ^ (lane & 7)) * 8;
#pragma unroll
      for (int s = 0; s < 4; s++) af[s] = *(const short8*)&as[(wm + s * 16 + li) * 64 + slot];
#pragma unroll
      for (int s = 0; s < 4; s++) bf[s] = *(const short8*)&bs[(wn + s * 16 + li) * 64 + slot];
#pragma unroll
      for (int si = 0; si < 4; si++)
#pragma unroll
        for (int sj = 0; sj < 4; sj++)
          acc[si][sj] = __builtin_amdgcn_mfma_f32_16x16x32_bf16(af[si], bf[sj], acc[si][sj], 0, 0, 0);
    }
    __builtin_amdgcn_s_barrier();                        // all reads of cur done
    cur ^= 1;
  }

#pragma unroll
  for (int si = 0; si < 4; si++)
#pragma unroll
    for (int sj = 0; sj < 4; sj++) {
      int n = n0 + wn + sj * 16 + li;                // n
      int m0 = wm + si * 16 + quad * 4;              // m base (multiple of 4)
      if (mode == 0) {
        f32x4 c4 = *(const f32x4*)&cb[(long)n * 256 + m0];
        us4v o;
#pragma unroll
        for (int r = 0; r < 4; r++) o[r] = f2b(acc[si][sj][r] + c4[r]);
        *(us4v*)&out16[(long)b * NB + (long)n * 256 + m0] = o;
      } else {
#pragma unroll
        for (int r = 0; r < 4; r++) {
          int m = m0 + r;
          float v = acc[si][sj][r] + cb[m];
          long a = (long)b * NB + (long)m * 4096 + n;
          float xv = xres[a];
          out32[a] = fmaf(v, xv, xv);
        }
      }
    }
}

// ---------------- host ----------------
extern "C" void kernel_launch(void* const* d_in, const int* in_sizes, int n_in,
                              void* d_out, int out_size, void* d_ws, size_t ws_size,
                              hipStream_t stream)
{
  const float* x   = (const float*)d_in[0];
  const float* qw  = (const float*)d_in[1];
  const float* qb  = (const float*)d_in[2];
  const float* kw  = (const float*)d_in[3];
  const float* kb  = (const float*)d_in[4];
  const float* vw  = (const float*)d_in[5];
  const float* vb  = (const float*)d_in[6];
  const float* rw  = (const float*)d_in[7];
  const float* rb  = (const float*)d_in[8];
  const float* c1w = (const float*)d_in[9];
  const float* c1b = (const float*)d_in[10];
  const float* c2w = (const float*)d_in[11];
  const float* c2b = (const float*)d_in[12];

  // ws layout (u16 units)
  u16* U     = (u16*)d_ws;
  u16* xT16  = U;                     // 8388608 ; later wvT16
  u16* Qt16  = U + 8388608;           // 8388608 ; later h1T16
  u16* KV16  = U + 16777216;          // 16777216 (K rows 0-255, V rows 256-511 per b)
  u16* wr2   = U + 33554432;          // 589824
  u16* kvT16 = U + 34144256;          // 524288
  float* Fws = (float*)(U + 34668544);
  float* ksum = Fws;                  // 2048
  float* vsum = Fws + 2048;           // 2048
  float* zbuf = Fws + 4096;           // 64 (zero page for conv OOB loads)

  // d_out scratch (all dead before conv2 writes d_out; conv2 reads NOTHING here)
  char* ob = (char*)d_out;
  float* kvpart = (float*)(ob + 0);           // 16777216 B
  float* den    = (float*)(ob + 16777216);    // 131072
  float* rsqK   = (float*)(ob + 16908288);    // 131072
  float* corr   = (float*)(ob + 17039360);    // 4194304  (layout [n][m])
  u16*   w1p16  = (u16*)(ob + 21233664);      // 1179648
  u16*   wr1    = (u16*)(ob + 22413312);      // 1179648
  float* T      = (float*)(ob + 23592960);    // 36864
  u16*   rwT16  = (u16*)(ob + 23629824);      // 131072
  u16*   qw16   = (u16*)(ob + 23760896);      // 131072
  u16*   kvw16  = (u16*)(ob + 23891968);      // 262144
  float* kvbias = (float*)(ob + 24154112);    // 2048
  float* rq     = (float*)(ob + 24158208);    // 131072 (qden output, dead by conv1)
  float* outF   = (float*)d_out;

  u16* wvT16 = xT16;
  u16* h1T16 = Qt16;

  dim3 blk(256);

  prep1<<<5889, blk, 0, stream>>>(qw, kw, vw, rw, c1w, c2w, kb, vb, rb,
                                  qw16, kvw16, rwT16, wr1, wr2, kvbias, zbuf, T);
  corr_transX<<<6144, blk, 0, stream>>>(T, c1b, corr, x, xT16);

  // w1' = wr1 @ rwT : folds rw into conv1 weights, layout [m][d*256+cv]
  gemm_nt<<<dim3(2, 18, 1), blk, 0, stream>>>(wr1, rwT16, w1p16,
      256, 256, 256, 0L, 0L, 0L, 256L, 1L, 0, nullptr, nullptr, nullptr);
  // Qt[b][n][ck] = xT @ qw^T + qb
  gemm_nt<<<dim3(2, 32, 8), blk, 0, stream>>>(xT16, qw16, Qt16,
      256, 256, 256, NB, 0L, NB, 256L, 1L, 0, nullptr, qb, nullptr);
  // KV[b][cq][n] = [kw|vw] @ x + [kb|vb]
  gemm_nt<<<dim3(32, 4, 8), blk, 0, stream>>>(kvw16, xT16, KV16,
      256, 256, 256, 0L, NB, 2 * NB, 4096L, 1L, 0, kvbias, nullptr, nullptr);

  sumsqK<<<512, blk, 0, stream>>>(KV16, rsqK);
  scale_sums<<<4096, blk, 0, stream>>>(KV16, rsqK, ksum, vsum);
  qden<<<8192, blk, 0, stream>>>(Qt16, ksum, rq, den);

  gemm_kv<<<dim3(2, 2, 64), blk, 0, stream>>>(KV16, kvpart);
  reduce_kv<<<2048, blk, 0, stream>>>(kvpart, kvT16);

  // wvT[b][n][cv] = (Q @ kv * rq + vsum)*den   (coalesced stores)
  gemm_nt<<<dim3(2, 32, 8), blk, 0, stream>>>(Qt16, kvT16, wvT16,
      256, 256, 256, NB, 65536L, NB, 256L, 1L, 2, vsum, den, rq);

  conv_gemm<<<256, 512, 0, stream>>>(wvT16, w1p16, corr, nullptr, zbuf,
                                     h1T16, nullptr, 0);
  conv_gemm<<<256, 512, 0, stream>>>(h1T16, wr2, c2b, x, zbuf,
                                     nullptr, outF, 1);
}